// Round 1
// baseline (902.653 us; speedup 1.0000x reference)
//
#include <hip/hip_runtime.h>
#include <hip/hip_bf16.h>

#define NN   50000
#define NE   800000
#define FIN  64
#define FHID 128
#define FOUT 2

// workspace layout (bytes):
//   deg  : int[NN]          @ 0          (200,000)
//   agg0 : float[NN*FIN]    @ 200,000    (12,800,000)
//   agg1 : float[NN*FHID]   @ 13,000,000 (25,600,000)
//   h0   : float[NN*FHID]   @ 38,600,000 (25,600,000)
// total: 64,200,000 bytes; first 38,600,000 must be zeroed each call.

__global__ __launch_bounds__(256) void scatter0_k(
    const float* __restrict__ x, const int* __restrict__ src,
    const int* __restrict__ dst, float* __restrict__ agg0,
    int* __restrict__ deg)
{
    int gid   = blockIdx.x * 256 + threadIdx.x;
    int lane  = gid & (FIN - 1);   // feature 0..63
    int slot  = gid >> 6;          // one 64-lane group per edge
    int nslot = (gridDim.x * 256) >> 6;
    for (int e = slot; e < NE; e += nslot) {
        int s = src[e];
        int d = dst[e];
        float v = x[s * FIN + lane];
        atomicAdd(&agg0[d * FIN + lane], v);
        if (lane == 0) atomicAdd(&deg[d], 1);
    }
}

__global__ __launch_bounds__(256) void scatter1_k(
    const float* __restrict__ h0, const int* __restrict__ src,
    const int* __restrict__ dst, float* __restrict__ agg1)
{
    int gid   = blockIdx.x * 256 + threadIdx.x;
    int lane  = gid & (FHID - 1);  // feature 0..127
    int slot  = gid >> 7;          // one 128-lane group per edge
    int nslot = (gridDim.x * 256) >> 7;
    for (int e = slot; e < NE; e += nslot) {
        int s = src[e];
        int d = dst[e];
        float v = h0[s * FHID + lane];
        atomicAdd(&agg1[d * FHID + lane], v);
    }
}

// h0[n,t] = relu( sum_k aggs[n,k]*Wl[t,k] + bl[t] + sum_k x[n,k]*Wr[t,k] )
__global__ __launch_bounds__(256) void dense0_k(
    const float* __restrict__ x, const float* __restrict__ agg0,
    const int* __restrict__ deg,
    const float* __restrict__ Wl, const float* __restrict__ bl,
    const float* __restrict__ Wr, float* __restrict__ h0)
{
    __shared__ __hip_bfloat16 WlT[FIN][FHID];   // [k][t], 16 KB
    __shared__ __hip_bfloat16 WrT[FIN][FHID];   // 16 KB
    __shared__ float inA[2][FIN];
    __shared__ float inX[2][FIN];

    for (int i = threadIdx.x; i < FHID * FIN; i += 256) {
        int r = i >> 6;   // out feature (row of W)
        int c = i & 63;   // in  feature
        WlT[c][r] = __float2bfloat16(Wl[i]);
        WrT[c][r] = __float2bfloat16(Wr[i]);
    }
    __syncthreads();

    int sub = threadIdx.x >> 7;    // which of 2 nodes this block-iter
    int t   = threadIdx.x & 127;   // output feature
    float bias = bl[t];

    for (int n0 = blockIdx.x * 2; n0 < NN; n0 += gridDim.x * 2) {
        int n = n0 + sub;
        if (n < NN) {
            if (t < FIN) {
                float sc = 1.0f / fmaxf((float)deg[n], 1.0f);
                inA[sub][t] = agg0[n * FIN + t] * sc;
            } else {
                inX[sub][t - FIN] = x[n * FIN + (t - FIN)];
            }
        }
        __syncthreads();
        if (n < NN) {
            float acc = bias;
            #pragma unroll
            for (int k = 0; k < FIN; ++k) {
                acc += inA[sub][k] * __bfloat162float(WlT[k][t]);
                acc += inX[sub][k] * __bfloat162float(WrT[k][t]);
            }
            h0[n * FHID + t] = fmaxf(acc, 0.0f);
        }
        __syncthreads();
    }
}

// h1[n,t] = relu( sum_k aggs1[n,k]*Wl1[t,k] + bl1[t] + sum_k h0[n,k]*Wr1[t,k] )
// out[n,o] = sum_t h1[n,t]*Wfc[o,t] + bfc[o]   (h1 never hits memory)
__global__ __launch_bounds__(256) void dense1_k(
    const float* __restrict__ h0, const float* __restrict__ agg1,
    const int* __restrict__ deg,
    const float* __restrict__ Wl, const float* __restrict__ bl,
    const float* __restrict__ Wr,
    const float* __restrict__ Wfc, const float* __restrict__ bfc,
    float* __restrict__ out)
{
    __shared__ __hip_bfloat16 WlT[FHID][FHID];  // [k][t], 32 KB
    __shared__ __hip_bfloat16 WrT[FHID][FHID];  // 32 KB
    __shared__ float inA[2][FHID];
    __shared__ float inH[2][FHID];
    __shared__ float wfc_s[2 * FHID];
    __shared__ float red[2][2][2];              // [sub][wave-in-sub][o]

    for (int i = threadIdx.x; i < FHID * FHID; i += 256) {
        int r = i >> 7, c = i & 127;
        WlT[c][r] = __float2bfloat16(Wl[i]);
        WrT[c][r] = __float2bfloat16(Wr[i]);
    }
    if (threadIdx.x < 2 * FHID) wfc_s[threadIdx.x] = Wfc[threadIdx.x];
    __syncthreads();

    int sub = threadIdx.x >> 7;
    int t   = threadIdx.x & 127;
    int wv  = (threadIdx.x >> 6) & 1;
    float bias = bl[t];

    for (int n0 = blockIdx.x * 2; n0 < NN; n0 += gridDim.x * 2) {
        int n = n0 + sub;
        if (n < NN) {
            float sc = 1.0f / fmaxf((float)deg[n], 1.0f);
            inA[sub][t] = agg1[n * FHID + t] * sc;
            inH[sub][t] = h0[n * FHID + t];
        }
        __syncthreads();
        float p0 = 0.f, p1 = 0.f;
        if (n < NN) {
            float acc = bias;
            #pragma unroll 8
            for (int k = 0; k < FHID; ++k) {
                acc += inA[sub][k] * __bfloat162float(WlT[k][t]);
                acc += inH[sub][k] * __bfloat162float(WrT[k][t]);
            }
            float h1 = fmaxf(acc, 0.0f);
            p0 = h1 * wfc_s[t];
            p1 = h1 * wfc_s[FHID + t];
        }
        #pragma unroll
        for (int off = 32; off > 0; off >>= 1) {
            p0 += __shfl_xor(p0, off, 64);
            p1 += __shfl_xor(p1, off, 64);
        }
        if ((threadIdx.x & 63) == 0) {
            red[sub][wv][0] = p0;
            red[sub][wv][1] = p1;
        }
        __syncthreads();
        if (n < NN && t < FOUT) {
            out[n * FOUT + t] = red[sub][0][t] + red[sub][1][t] + bfc[t];
        }
        __syncthreads();
    }
}

extern "C" void kernel_launch(void* const* d_in, const int* in_sizes, int n_in,
                              void* d_out, int out_size, void* d_ws, size_t ws_size,
                              hipStream_t stream)
{
    const float* x   = (const float*)d_in[0];
    const int*   ei  = (const int*)d_in[1];
    const float* Wl0 = (const float*)d_in[2];
    const float* bl0 = (const float*)d_in[3];
    const float* Wr0 = (const float*)d_in[4];
    const float* Wl1 = (const float*)d_in[5];
    const float* bl1 = (const float*)d_in[6];
    const float* Wr1 = (const float*)d_in[7];
    const float* Wfc = (const float*)d_in[8];
    const float* bfc = (const float*)d_in[9];
    float* out = (float*)d_out;

    const int* src = ei;        // edge_index[0]
    const int* dst = ei + NE;   // edge_index[1]

    char*  ws   = (char*)d_ws;
    int*   deg  = (int*)(ws);
    float* agg0 = (float*)(ws + 200000);
    float* agg1 = (float*)(ws + 13000000);
    float* h0   = (float*)(ws + 38600000);

    // zero deg + agg0 + agg1 (h0 is fully overwritten by dense0)
    hipMemsetAsync(d_ws, 0, 38600000, stream);

    scatter0_k<<<2048, 256, 0, stream>>>(x, src, dst, agg0, deg);
    dense0_k  <<<1024, 256, 0, stream>>>(x, agg0, deg, Wl0, bl0, Wr0, h0);
    scatter1_k<<<2048, 256, 0, stream>>>(h0, src, dst, agg1);
    dense1_k  <<<1024, 256, 0, stream>>>(h0, agg1, deg, Wl1, bl1, Wr1, Wfc, bfc, out);
}

// Round 2
// 670.521 us; speedup vs baseline: 1.3462x; 1.3462x over previous
//
#include <hip/hip_runtime.h>
#include <hip/hip_bf16.h>

#define NN   50000
#define NE   800000
#define FIN  64
#define FHID 128
#define FOUT 2

// workspace layout (bytes), all 16-aligned where needed:
//   deg    : int[NN]       @ 0           (200,000)   <- memset to 0 each call
//   rowptr : int[NN+1]     @ 200,000     (200,004)
//   cursor : int[NN]       @ 400,004     (200,000)
//   nbr    : int[NE]       @ 600,004     (3,200,000)
//   aggU   : float[NN*128] @ 3,800,016   (25,600,000)  agg0 (NN*64) and agg1 (NN*128) share
//   h0     : float[NN*128] @ 29,400,016  (25,600,000)
// total 55,000,016 bytes

__global__ __launch_bounds__(256) void count_k(
    const int* __restrict__ dst, int* __restrict__ deg)
{
    int gid = blockIdx.x * 256 + threadIdx.x;
    int stride = gridDim.x * 256;
    for (int e = gid; e < NE; e += stride)
        atomicAdd(&deg[dst[e]], 1);
}

__global__ __launch_bounds__(1024) void scan_k(
    const int* __restrict__ deg, int* __restrict__ rowptr,
    int* __restrict__ cursor)
{
    __shared__ int sums[1024];
    int tid = threadIdx.x;
    const int C = (NN + 1023) / 1024;      // 49 elements per thread
    int start = tid * C;
    int end   = start + C < NN ? start + C : NN;
    if (start > NN) start = NN;
    int s = 0;
    for (int i = start; i < end; ++i) s += deg[i];
    sums[tid] = s;
    __syncthreads();
    for (int off = 1; off < 1024; off <<= 1) {
        int add = (tid >= off) ? sums[tid - off] : 0;
        __syncthreads();
        sums[tid] += add;
        __syncthreads();
    }
    int run = (tid == 0) ? 0 : sums[tid - 1];   // exclusive prefix
    for (int i = start; i < end; ++i) {
        rowptr[i] = run;
        cursor[i] = run;
        run += deg[i];
    }
    if (tid == 1023) rowptr[NN] = run;          // == NE
}

__global__ __launch_bounds__(256) void fill_k(
    const int* __restrict__ src, const int* __restrict__ dst,
    int* __restrict__ cursor, int* __restrict__ nbr)
{
    int gid = blockIdx.x * 256 + threadIdx.x;
    int stride = gridDim.x * 256;
    for (int e = gid; e < NE; e += stride) {
        int d = dst[e];
        int pos = atomicAdd(&cursor[d], 1);
        nbr[pos] = src[e];
    }
}

// one 64-lane wave per node: lane = feature, registers accumulate mean(x[nbrs])
__global__ __launch_bounds__(256) void gather0_k(
    const float* __restrict__ x, const int* __restrict__ rowptr,
    const int* __restrict__ nbr, float* __restrict__ agg0)
{
    int gid  = blockIdx.x * 256 + threadIdx.x;
    int lane = gid & 63;
    int node = gid >> 6;
    if (node >= NN) return;
    int b = rowptr[node], e2 = rowptr[node + 1];
    float acc = 0.f;
    #pragma unroll 2
    for (int e = b; e < e2; ++e) {
        int s = nbr[e];                       // uniform across wave -> broadcast
        acc += x[s * FIN + lane];
    }
    float inv = 1.0f / fmaxf((float)(e2 - b), 1.0f);
    agg0[node * FIN + lane] = acc * inv;
}

// one 64-lane wave per node, float2 per lane (128 features)
__global__ __launch_bounds__(256) void gather1_k(
    const float* __restrict__ h0, const int* __restrict__ rowptr,
    const int* __restrict__ nbr, float* __restrict__ agg1)
{
    int gid  = blockIdx.x * 256 + threadIdx.x;
    int lane = gid & 63;
    int node = gid >> 6;
    if (node >= NN) return;
    int b = rowptr[node], e2 = rowptr[node + 1];
    const float2* h2 = (const float2*)h0;
    float2 acc = {0.f, 0.f};
    #pragma unroll 2
    for (int e = b; e < e2; ++e) {
        int s = nbr[e];
        float2 v = h2[s * 64 + lane];
        acc.x += v.x; acc.y += v.y;
    }
    float inv = 1.0f / fmaxf((float)(e2 - b), 1.0f);
    float2* a2 = (float2*)agg1;
    float2 o; o.x = acc.x * inv; o.y = acc.y * inv;
    a2[node * 64 + lane] = o;
}

// h0[n,t] = relu( sum_k agg0[n,k]*Wl[t,k] + bl[t] + sum_k x[n,k]*Wr[t,k] )
__global__ __launch_bounds__(256) void dense0_k(
    const float* __restrict__ x, const float* __restrict__ agg0,
    const int* __restrict__ rowptr,
    const float* __restrict__ Wl, const float* __restrict__ bl,
    const float* __restrict__ Wr, float* __restrict__ h0)
{
    __shared__ __hip_bfloat16 WlT[FIN][FHID];   // [k][t], 16 KB
    __shared__ __hip_bfloat16 WrT[FIN][FHID];   // 16 KB
    __shared__ float inA[2][FIN];
    __shared__ float inX[2][FIN];

    for (int i = threadIdx.x; i < FHID * FIN; i += 256) {
        int r = i >> 6;   // out feature
        int c = i & 63;   // in  feature
        WlT[c][r] = __float2bfloat16(Wl[i]);
        WrT[c][r] = __float2bfloat16(Wr[i]);
    }
    __syncthreads();

    int sub = threadIdx.x >> 7;
    int t   = threadIdx.x & 127;
    float bias = bl[t];

    for (int n0 = blockIdx.x * 2; n0 < NN; n0 += gridDim.x * 2) {
        int n = n0 + sub;
        if (n < NN) {
            if (t < FIN) {
                inA[sub][t] = agg0[n * FIN + t];
            } else {
                inX[sub][t - FIN] = x[n * FIN + (t - FIN)];
            }
        }
        __syncthreads();
        if (n < NN) {
            float acc = bias;
            #pragma unroll
            for (int k = 0; k < FIN; ++k) {
                acc += inA[sub][k] * __bfloat162float(WlT[k][t]);
                acc += inX[sub][k] * __bfloat162float(WrT[k][t]);
            }
            h0[n * FHID + t] = fmaxf(acc, 0.0f);
        }
        __syncthreads();
    }
}

// h1 = relu(agg1@Wl1^T + bl1 + h0@Wr1^T); out = h1@Wfc^T + bfc (h1 stays in regs)
__global__ __launch_bounds__(256) void dense1_k(
    const float* __restrict__ h0, const float* __restrict__ agg1,
    const int* __restrict__ rowptr,
    const float* __restrict__ Wl, const float* __restrict__ bl,
    const float* __restrict__ Wr,
    const float* __restrict__ Wfc, const float* __restrict__ bfc,
    float* __restrict__ out)
{
    __shared__ __hip_bfloat16 WlT[FHID][FHID];  // [k][t], 32 KB
    __shared__ __hip_bfloat16 WrT[FHID][FHID];  // 32 KB
    __shared__ float inA[2][FHID];
    __shared__ float inH[2][FHID];
    __shared__ float wfc_s[2 * FHID];
    __shared__ float red[2][2][2];

    for (int i = threadIdx.x; i < FHID * FHID; i += 256) {
        int r = i >> 7, c = i & 127;
        WlT[c][r] = __float2bfloat16(Wl[i]);
        WrT[c][r] = __float2bfloat16(Wr[i]);
    }
    if (threadIdx.x < 2 * FHID) wfc_s[threadIdx.x] = Wfc[threadIdx.x];
    __syncthreads();

    int sub = threadIdx.x >> 7;
    int t   = threadIdx.x & 127;
    int wv  = (threadIdx.x >> 6) & 1;
    float bias = bl[t];

    for (int n0 = blockIdx.x * 2; n0 < NN; n0 += gridDim.x * 2) {
        int n = n0 + sub;
        if (n < NN) {
            inA[sub][t] = agg1[n * FHID + t];
            inH[sub][t] = h0[n * FHID + t];
        }
        __syncthreads();
        float p0 = 0.f, p1 = 0.f;
        if (n < NN) {
            float acc = bias;
            #pragma unroll 8
            for (int k = 0; k < FHID; ++k) {
                acc += inA[sub][k] * __bfloat162float(WlT[k][t]);
                acc += inH[sub][k] * __bfloat162float(WrT[k][t]);
            }
            float h1 = fmaxf(acc, 0.0f);
            p0 = h1 * wfc_s[t];
            p1 = h1 * wfc_s[FHID + t];
        }
        #pragma unroll
        for (int off = 32; off > 0; off >>= 1) {
            p0 += __shfl_xor(p0, off, 64);
            p1 += __shfl_xor(p1, off, 64);
        }
        if ((threadIdx.x & 63) == 0) {
            red[sub][wv][0] = p0;
            red[sub][wv][1] = p1;
        }
        __syncthreads();
        if (n < NN && t < FOUT) {
            out[n * FOUT + t] = red[sub][0][t] + red[sub][1][t] + bfc[t];
        }
        __syncthreads();
    }
}

extern "C" void kernel_launch(void* const* d_in, const int* in_sizes, int n_in,
                              void* d_out, int out_size, void* d_ws, size_t ws_size,
                              hipStream_t stream)
{
    const float* x   = (const float*)d_in[0];
    const int*   ei  = (const int*)d_in[1];
    const float* Wl0 = (const float*)d_in[2];
    const float* bl0 = (const float*)d_in[3];
    const float* Wr0 = (const float*)d_in[4];
    const float* Wl1 = (const float*)d_in[5];
    const float* bl1 = (const float*)d_in[6];
    const float* Wr1 = (const float*)d_in[7];
    const float* Wfc = (const float*)d_in[8];
    const float* bfc = (const float*)d_in[9];
    float* out = (float*)d_out;

    const int* src = ei;        // edge_index[0]
    const int* dst = ei + NE;   // edge_index[1]

    char*  ws     = (char*)d_ws;
    int*   deg    = (int*)(ws);
    int*   rowptr = (int*)(ws + 200000);
    int*   cursor = (int*)(ws + 400004);
    int*   nbr    = (int*)(ws + 600004);
    float* aggU   = (float*)(ws + 3800016);   // agg0 then agg1 (lifetimes disjoint)
    float* h0     = (float*)(ws + 29400016);

    hipMemsetAsync(deg, 0, 200000, stream);   // deg only

    count_k <<<3125, 256, 0, stream>>>(dst, deg);
    scan_k  <<<1, 1024, 0, stream>>>(deg, rowptr, cursor);
    fill_k  <<<3125, 256, 0, stream>>>(src, dst, cursor, nbr);

    gather0_k<<<12500, 256, 0, stream>>>(x, rowptr, nbr, aggU);
    dense0_k <<<1024, 256, 0, stream>>>(x, aggU, rowptr, Wl0, bl0, Wr0, h0);
    gather1_k<<<12500, 256, 0, stream>>>(h0, rowptr, nbr, aggU);
    dense1_k <<<1024, 256, 0, stream>>>(h0, aggU, rowptr, Wl1, bl1, Wr1, Wfc, bfc, out);
}

// Round 3
// 389.465 us; speedup vs baseline: 2.3177x; 1.7216x over previous
//
#include <hip/hip_runtime.h>
#include <hip/hip_bf16.h>

#define NN   50000
#define NE   800000

typedef __attribute__((ext_vector_type(8))) short short8;
typedef __attribute__((ext_vector_type(4))) float f32x4;

static __device__ __forceinline__ ushort f2bf(float f) {
    union { float f; unsigned u; } v; v.f = f;
    unsigned r = v.u + 0x7fffu + ((v.u >> 16) & 1u);   // round-to-nearest-even
    return (ushort)(r >> 16);
}
static __device__ __forceinline__ float bf2f(ushort h) {
    union { unsigned u; float f; } v; v.u = ((unsigned)h) << 16;
    return v.f;
}

// ---------------- CSR build ----------------
__global__ __launch_bounds__(256) void count_k(
    const int* __restrict__ dst, int* __restrict__ deg)
{
    int gid = blockIdx.x * 256 + threadIdx.x;
    int stride = gridDim.x * 256;
    for (int e = gid; e < NE; e += stride)
        atomicAdd(&deg[dst[e]], 1);
}

__global__ __launch_bounds__(1024) void scan_k(
    const int* __restrict__ deg, int* __restrict__ rowptr,
    int* __restrict__ cursor)
{
    __shared__ int sums[1024];
    int tid = threadIdx.x;
    const int C = (NN + 1023) / 1024;
    int start = tid * C;
    int end   = start + C < NN ? start + C : NN;
    if (start > NN) start = NN;
    int s = 0;
    for (int i = start; i < end; ++i) s += deg[i];
    sums[tid] = s;
    __syncthreads();
    for (int off = 1; off < 1024; off <<= 1) {
        int add = (tid >= off) ? sums[tid - off] : 0;
        __syncthreads();
        sums[tid] += add;
        __syncthreads();
    }
    int run = (tid == 0) ? 0 : sums[tid - 1];
    for (int i = start; i < end; ++i) {
        rowptr[i] = run;
        cursor[i] = run;
        run += deg[i];
    }
    if (tid == 1023) rowptr[NN] = run;
}

__global__ __launch_bounds__(256) void fill_k(
    const int* __restrict__ src, const int* __restrict__ dst,
    int* __restrict__ cursor, int* __restrict__ nbr)
{
    int gid = blockIdx.x * 256 + threadIdx.x;
    int stride = gridDim.x * 256;
    for (int e = gid; e < NE; e += stride) {
        int d = dst[e];
        int pos = atomicAdd(&cursor[d], 1);
        nbr[pos] = src[e];
    }
}

// ---------------- gathers (mean-aggregate), bf16 out ----------------
__global__ __launch_bounds__(256) void gather0_k(
    const float* __restrict__ x, const int* __restrict__ rowptr,
    const int* __restrict__ nbr, ushort* __restrict__ agg0)
{
    int gid  = blockIdx.x * 256 + threadIdx.x;
    int lane = gid & 63;
    int node = gid >> 6;
    if (node >= NN) return;
    int b = rowptr[node], e2 = rowptr[node + 1];
    float acc = 0.f;
    for (int e = b; e < e2; ++e) {
        int s = nbr[e];                    // wave-uniform -> broadcast
        acc += x[s * 64 + lane];
    }
    float inv = 1.0f / fmaxf((float)(e2 - b), 1.0f);
    agg0[node * 64 + lane] = f2bf(acc * inv);
}

__global__ __launch_bounds__(256) void gather1_k(
    const ushort* __restrict__ h0, const int* __restrict__ rowptr,
    const int* __restrict__ nbr, ushort* __restrict__ agg1)
{
    int gid  = blockIdx.x * 256 + threadIdx.x;
    int lane = gid & 63;
    int node = gid >> 6;
    if (node >= NN) return;
    int b = rowptr[node], e2 = rowptr[node + 1];
    const unsigned* h2 = (const unsigned*)h0;   // 2 bf16 per load
    float a0 = 0.f, a1 = 0.f;
    for (int e = b; e < e2; ++e) {
        unsigned v = h2[nbr[e] * 64 + lane];
        a0 += bf2f((ushort)(v & 0xffffu));
        a1 += bf2f((ushort)(v >> 16));
    }
    float inv = 1.0f / fmaxf((float)(e2 - b), 1.0f);
    unsigned o = (unsigned)f2bf(a0 * inv) | ((unsigned)f2bf(a1 * inv) << 16);
    ((unsigned*)agg1)[node * 64 + lane] = o;
}

// ---------------- dense0: h0 = relu([agg0|x] @ [Wl0;Wr0]^T + bl0), MFMA ----------------
// block: 64 rows x 128 cols, 4 waves (16 rows each). K=128 (64 agg + 64 x).
__global__ __launch_bounds__(256) void dense0_k(
    const float* __restrict__ x, const ushort* __restrict__ agg0,
    const float* __restrict__ Wl, const float* __restrict__ bl,
    const float* __restrict__ Wr, ushort* __restrict__ h0)
{
    __shared__ ushort bt[128 * 128];   // B_T[n][k] bf16, XOR-swizzled, 32 KB
    __shared__ float  bl_s[128];

    // fill B_T: row n = concat(Wl0[n][0:64], Wr0[n][0:64]); 8-elem chunks along k
    for (int c = threadIdx.x; c < 2048; c += 256) {
        int n  = c >> 4;
        int kc = (c & 15) * 8;
        const float* wsrc = (kc < 64) ? (Wl + n * 64 + kc) : (Wr + n * 64 + (kc - 64));
        float4 f0 = *(const float4*)(wsrc);
        float4 f1 = *(const float4*)(wsrc + 4);
        short8 v;
        v[0] = f2bf(f0.x); v[1] = f2bf(f0.y); v[2] = f2bf(f0.z); v[3] = f2bf(f0.w);
        v[4] = f2bf(f1.x); v[5] = f2bf(f1.y); v[6] = f2bf(f1.z); v[7] = f2bf(f1.w);
        int byte = (n * 256 + kc * 2) ^ ((n & 7) << 4);
        *(short8*)((char*)bt + byte) = v;
    }
    if (threadIdx.x < 128) bl_s[threadIdx.x] = bl[threadIdx.x];
    __syncthreads();

    int w = threadIdx.x >> 6, l = threadIdx.x & 63;
    int l15 = l & 15, hi = l >> 4;
    int row  = blockIdx.x * 64 + w * 16 + l15;
    int rowc = row < NN ? row : 0;

    short8 a[4];
    a[0] = *(const short8*)(agg0 + rowc * 64 + hi * 8);
    a[1] = *(const short8*)(agg0 + rowc * 64 + 32 + hi * 8);
    #pragma unroll
    for (int ks = 0; ks < 2; ++ks) {
        const float* xp = x + rowc * 64 + ks * 32 + hi * 8;
        float4 f0 = *(const float4*)(xp);
        float4 f1 = *(const float4*)(xp + 4);
        short8 v;
        v[0] = f2bf(f0.x); v[1] = f2bf(f0.y); v[2] = f2bf(f0.z); v[3] = f2bf(f0.w);
        v[4] = f2bf(f1.x); v[5] = f2bf(f1.y); v[6] = f2bf(f1.z); v[7] = f2bf(f1.w);
        a[2 + ks] = v;
    }

    f32x4 acc[8];
    #pragma unroll
    for (int nt = 0; nt < 8; ++nt) acc[nt] = (f32x4){0.f, 0.f, 0.f, 0.f};

    #pragma unroll
    for (int ks = 0; ks < 4; ++ks) {
        #pragma unroll
        for (int nt = 0; nt < 8; ++nt) {
            int byte = ((nt * 16 + l15) * 256 + (ks * 32 + hi * 8) * 2) ^ ((l15 & 7) << 4);
            short8 bfr = *(const short8*)((const char*)bt + byte);
            acc[nt] = __builtin_amdgcn_mfma_f32_16x16x32_bf16(a[ks], bfr, acc[nt], 0, 0, 0);
        }
    }

    int rowbase = blockIdx.x * 64 + w * 16 + hi * 4;
    #pragma unroll
    for (int r = 0; r < 4; ++r) {
        int ro = rowbase + r;
        if (ro < NN) {
            #pragma unroll
            for (int nt = 0; nt < 8; ++nt) {
                int col = nt * 16 + l15;
                float v = fmaxf(acc[nt][r] + bl_s[col], 0.f);
                h0[ro * 128 + col] = f2bf(v);
            }
        }
    }
}

// ---------------- dense1 + fc fused: out = (relu([agg1|h0]@[Wl1;Wr1]^T + bl1)) @ Wfc^T + bfc
// block: 64 rows x 128 cols, 4 waves. K=256.
__global__ __launch_bounds__(256) void dense1_k(
    const ushort* __restrict__ h0, const ushort* __restrict__ agg1,
    const float* __restrict__ Wl, const float* __restrict__ bl,
    const float* __restrict__ Wr,
    const float* __restrict__ Wfc, const float* __restrict__ bfc,
    float* __restrict__ out)
{
    __shared__ ushort bt[256 * 128];   // B_T[n][k] bf16, 64 KB, XOR-swizzled
    __shared__ float  bl_s[128];
    __shared__ float  wfc_s[256];

    for (int c = threadIdx.x; c < 4096; c += 256) {
        int n  = c >> 5;
        int kc = (c & 31) * 8;
        const float* wsrc = (kc < 128) ? (Wl + n * 128 + kc) : (Wr + n * 128 + (kc - 128));
        float4 f0 = *(const float4*)(wsrc);
        float4 f1 = *(const float4*)(wsrc + 4);
        short8 v;
        v[0] = f2bf(f0.x); v[1] = f2bf(f0.y); v[2] = f2bf(f0.z); v[3] = f2bf(f0.w);
        v[4] = f2bf(f1.x); v[5] = f2bf(f1.y); v[6] = f2bf(f1.z); v[7] = f2bf(f1.w);
        int byte = (n * 512 + kc * 2) ^ ((n & 7) << 4);
        *(short8*)((char*)bt + byte) = v;
    }
    if (threadIdx.x < 128) bl_s[threadIdx.x] = bl[threadIdx.x];
    if (threadIdx.x < 256) wfc_s[threadIdx.x] = Wfc[threadIdx.x];
    __syncthreads();

    int w = threadIdx.x >> 6, l = threadIdx.x & 63;
    int l15 = l & 15, hi = l >> 4;
    int row  = blockIdx.x * 64 + w * 16 + l15;
    int rowc = row < NN ? row : 0;

    short8 a[8];
    #pragma unroll
    for (int ks = 0; ks < 4; ++ks)
        a[ks] = *(const short8*)(agg1 + rowc * 128 + ks * 32 + hi * 8);
    #pragma unroll
    for (int ks = 0; ks < 4; ++ks)
        a[4 + ks] = *(const short8*)(h0 + rowc * 128 + ks * 32 + hi * 8);

    f32x4 acc[8];
    #pragma unroll
    for (int nt = 0; nt < 8; ++nt) acc[nt] = (f32x4){0.f, 0.f, 0.f, 0.f};

    #pragma unroll
    for (int ks = 0; ks < 8; ++ks) {
        #pragma unroll
        for (int nt = 0; nt < 8; ++nt) {
            int byte = ((nt * 16 + l15) * 512 + (ks * 32 + hi * 8) * 2) ^ ((l15 & 7) << 4);
            short8 bfr = *(const short8*)((const char*)bt + byte);
            acc[nt] = __builtin_amdgcn_mfma_f32_16x16x32_bf16(a[ks], bfr, acc[nt], 0, 0, 0);
        }
    }

    // epilogue: per reg r -> one output row; relu+bias, dot with Wfc (2 outs),
    // reduce across the 16 lanes (l15) that share the row.
    int rowbase = blockIdx.x * 64 + w * 16 + hi * 4;
    #pragma unroll
    for (int r = 0; r < 4; ++r) {
        float p0 = 0.f, p1 = 0.f;
        #pragma unroll
        for (int nt = 0; nt < 8; ++nt) {
            int col = nt * 16 + l15;
            float h1 = fmaxf(acc[nt][r] + bl_s[col], 0.f);
            p0 += h1 * wfc_s[col];
            p1 += h1 * wfc_s[128 + col];
        }
        p0 += __shfl_xor(p0, 1, 64); p0 += __shfl_xor(p0, 2, 64);
        p0 += __shfl_xor(p0, 4, 64); p0 += __shfl_xor(p0, 8, 64);
        p1 += __shfl_xor(p1, 1, 64); p1 += __shfl_xor(p1, 2, 64);
        p1 += __shfl_xor(p1, 4, 64); p1 += __shfl_xor(p1, 8, 64);
        int ro = rowbase + r;
        if (l15 == 0 && ro < NN) {
            float2 o; o.x = p0 + bfc[0]; o.y = p1 + bfc[1];
            *(float2*)(out + ro * 2) = o;
        }
    }
}

extern "C" void kernel_launch(void* const* d_in, const int* in_sizes, int n_in,
                              void* d_out, int out_size, void* d_ws, size_t ws_size,
                              hipStream_t stream)
{
    const float* x   = (const float*)d_in[0];
    const int*   ei  = (const int*)d_in[1];
    const float* Wl0 = (const float*)d_in[2];
    const float* bl0 = (const float*)d_in[3];
    const float* Wr0 = (const float*)d_in[4];
    const float* Wl1 = (const float*)d_in[5];
    const float* bl1 = (const float*)d_in[6];
    const float* Wr1 = (const float*)d_in[7];
    const float* Wfc = (const float*)d_in[8];
    const float* bfc = (const float*)d_in[9];
    float* out = (float*)d_out;

    const int* src = ei;
    const int* dst = ei + NE;

    // ws: deg@0 rowptr@200000 cursor@400004 nbr@600004 aggB@3800016 h0B@16600016
    char*   ws     = (char*)d_ws;
    int*    deg    = (int*)(ws);
    int*    rowptr = (int*)(ws + 200000);
    int*    cursor = (int*)(ws + 400004);
    int*    nbr    = (int*)(ws + 600004);
    ushort* aggB   = (ushort*)(ws + 3800016);   // agg0 (NN*64) then agg1 (NN*128), disjoint lifetimes
    ushort* h0B    = (ushort*)(ws + 16600016);

    hipMemsetAsync(deg, 0, 200000, stream);

    count_k <<<3125, 256, 0, stream>>>(dst, deg);
    scan_k  <<<1, 1024, 0, stream>>>(deg, rowptr, cursor);
    fill_k  <<<3125, 256, 0, stream>>>(src, dst, cursor, nbr);

    gather0_k<<<12500, 256, 0, stream>>>(x, rowptr, nbr, aggB);
    dense0_k <<<782, 256, 0, stream>>>(x, aggB, Wl0, bl0, Wr0, h0B);
    gather1_k<<<12500, 256, 0, stream>>>(h0B, rowptr, nbr, aggB);
    dense1_k <<<782, 256, 0, stream>>>(h0B, aggB, Wl1, bl1, Wr1, Wfc, bfc, out);
}

// Round 4
// 288.377 us; speedup vs baseline: 3.1301x; 1.3505x over previous
//
#include <hip/hip_runtime.h>
#include <hip/hip_bf16.h>

#define NN   50000
#define NE   800000
#define NB   196   // ceil(NN/256)

typedef __attribute__((ext_vector_type(8))) short short8;
typedef __attribute__((ext_vector_type(4))) float f32x4;

static __device__ __forceinline__ ushort f2bf(float f) {
    union { float f; unsigned u; } v; v.f = f;
    unsigned r = v.u + 0x7fffu + ((v.u >> 16) & 1u);   // round-to-nearest-even
    return (ushort)(r >> 16);
}
static __device__ __forceinline__ float bf2f(ushort h) {
    union { unsigned u; float f; } v; v.u = ((unsigned)h) << 16;
    return v.f;
}

// ---------------- CSR build ----------------
__global__ __launch_bounds__(256) void count_k(
    const int* __restrict__ dst, int* __restrict__ deg)
{
    int gid = blockIdx.x * 256 + threadIdx.x;
    int stride = gridDim.x * 256;
    for (int e = gid; e < NE; e += stride)
        atomicAdd(&deg[dst[e]], 1);
}

// per-256-chunk sums
__global__ __launch_bounds__(256) void partial_k(
    const int* __restrict__ deg, int* __restrict__ bsum)
{
    int gid = blockIdx.x * 256 + threadIdx.x;
    int v = (gid < NN) ? deg[gid] : 0;
    #pragma unroll
    for (int off = 32; off > 0; off >>= 1) v += __shfl_xor(v, off, 64);
    __shared__ int wsum[4];
    if ((threadIdx.x & 63) == 0) wsum[threadIdx.x >> 6] = v;
    __syncthreads();
    if (threadIdx.x == 0)
        bsum[blockIdx.x] = wsum[0] + wsum[1] + wsum[2] + wsum[3];
}

// exclusive scan of the NB block sums (single tiny block)
__global__ __launch_bounds__(256) void scanb_k(
    const int* __restrict__ bsum, int* __restrict__ boff,
    int* __restrict__ rowptr)
{
    __shared__ int s[256];
    int tid = threadIdx.x;
    int v = (tid < NB) ? bsum[tid] : 0;
    s[tid] = v;
    __syncthreads();
    for (int off = 1; off < 256; off <<= 1) {
        int add = (tid >= off) ? s[tid - off] : 0;
        __syncthreads();
        s[tid] += add;
        __syncthreads();
    }
    if (tid < NB) boff[tid] = s[tid] - v;       // exclusive prefix
    if (tid == 255) rowptr[NN] = s[255];        // total == NE
}

// per-chunk exclusive scan + block offset -> rowptr/cursor
__global__ __launch_bounds__(256) void emit_k(
    const int* __restrict__ deg, const int* __restrict__ boff,
    int* __restrict__ rowptr, int* __restrict__ cursor)
{
    __shared__ int s[256];
    int gid = blockIdx.x * 256 + threadIdx.x;
    int tid = threadIdx.x;
    int v = (gid < NN) ? deg[gid] : 0;
    s[tid] = v;
    __syncthreads();
    for (int off = 1; off < 256; off <<= 1) {
        int add = (tid >= off) ? s[tid - off] : 0;
        __syncthreads();
        s[tid] += add;
        __syncthreads();
    }
    if (gid < NN) {
        int excl = boff[blockIdx.x] + s[tid] - v;
        rowptr[gid] = excl;
        cursor[gid] = excl;
    }
}

__global__ __launch_bounds__(256) void fill_k(
    const int* __restrict__ src, const int* __restrict__ dst,
    int* __restrict__ cursor, int* __restrict__ nbr)
{
    int gid = blockIdx.x * 256 + threadIdx.x;
    int stride = gridDim.x * 256;
    for (int e = gid; e < NE; e += stride) {
        int d = dst[e];
        int pos = atomicAdd(&cursor[d], 1);
        nbr[pos] = src[e];
    }
}

// ---------------- gathers (mean-aggregate), bf16 out ----------------
__global__ __launch_bounds__(256) void gather0_k(
    const float* __restrict__ x, const int* __restrict__ rowptr,
    const int* __restrict__ nbr, ushort* __restrict__ agg0)
{
    int gid  = blockIdx.x * 256 + threadIdx.x;
    int lane = gid & 63;
    int node = gid >> 6;
    if (node >= NN) return;
    int b = rowptr[node], e2 = rowptr[node + 1];
    float acc = 0.f;
    for (int e = b; e < e2; ++e) {
        int s = nbr[e];                    // wave-uniform -> broadcast
        acc += x[s * 64 + lane];
    }
    float inv = 1.0f / fmaxf((float)(e2 - b), 1.0f);
    agg0[node * 64 + lane] = f2bf(acc * inv);
}

__global__ __launch_bounds__(256) void gather1_k(
    const ushort* __restrict__ h0, const int* __restrict__ rowptr,
    const int* __restrict__ nbr, ushort* __restrict__ agg1)
{
    int gid  = blockIdx.x * 256 + threadIdx.x;
    int lane = gid & 63;
    int node = gid >> 6;
    if (node >= NN) return;
    int b = rowptr[node], e2 = rowptr[node + 1];
    const unsigned* h2 = (const unsigned*)h0;   // 2 bf16 per load
    float a0 = 0.f, a1 = 0.f;
    for (int e = b; e < e2; ++e) {
        unsigned v = h2[nbr[e] * 64 + lane];
        a0 += bf2f((ushort)(v & 0xffffu));
        a1 += bf2f((ushort)(v >> 16));
    }
    float inv = 1.0f / fmaxf((float)(e2 - b), 1.0f);
    unsigned o = (unsigned)f2bf(a0 * inv) | ((unsigned)f2bf(a1 * inv) << 16);
    ((unsigned*)agg1)[node * 64 + lane] = o;
}

// ---------------- dense0: h0 = relu([agg0|x] @ [Wl0;Wr0]^T + bl0), MFMA ----------------
__global__ __launch_bounds__(256) void dense0_k(
    const float* __restrict__ x, const ushort* __restrict__ agg0,
    const float* __restrict__ Wl, const float* __restrict__ bl,
    const float* __restrict__ Wr, ushort* __restrict__ h0)
{
    __shared__ ushort bt[128 * 128];   // B_T[n][k] bf16, XOR-swizzled, 32 KB
    __shared__ float  bl_s[128];

    for (int c = threadIdx.x; c < 2048; c += 256) {
        int n  = c >> 4;
        int kc = (c & 15) * 8;
        const float* wsrc = (kc < 64) ? (Wl + n * 64 + kc) : (Wr + n * 64 + (kc - 64));
        float4 f0 = *(const float4*)(wsrc);
        float4 f1 = *(const float4*)(wsrc + 4);
        short8 v;
        v[0] = f2bf(f0.x); v[1] = f2bf(f0.y); v[2] = f2bf(f0.z); v[3] = f2bf(f0.w);
        v[4] = f2bf(f1.x); v[5] = f2bf(f1.y); v[6] = f2bf(f1.z); v[7] = f2bf(f1.w);
        int byte = (n * 256 + kc * 2) ^ ((n & 7) << 4);
        *(short8*)((char*)bt + byte) = v;
    }
    if (threadIdx.x < 128) bl_s[threadIdx.x] = bl[threadIdx.x];
    __syncthreads();

    int w = threadIdx.x >> 6, l = threadIdx.x & 63;
    int l15 = l & 15, hi = l >> 4;
    int row  = blockIdx.x * 64 + w * 16 + l15;
    int rowc = row < NN ? row : 0;

    short8 a[4];
    a[0] = *(const short8*)(agg0 + rowc * 64 + hi * 8);
    a[1] = *(const short8*)(agg0 + rowc * 64 + 32 + hi * 8);
    #pragma unroll
    for (int ks = 0; ks < 2; ++ks) {
        const float* xp = x + rowc * 64 + ks * 32 + hi * 8;
        float4 f0 = *(const float4*)(xp);
        float4 f1 = *(const float4*)(xp + 4);
        short8 v;
        v[0] = f2bf(f0.x); v[1] = f2bf(f0.y); v[2] = f2bf(f0.z); v[3] = f2bf(f0.w);
        v[4] = f2bf(f1.x); v[5] = f2bf(f1.y); v[6] = f2bf(f1.z); v[7] = f2bf(f1.w);
        a[2 + ks] = v;
    }

    f32x4 acc[8];
    #pragma unroll
    for (int nt = 0; nt < 8; ++nt) acc[nt] = (f32x4){0.f, 0.f, 0.f, 0.f};

    #pragma unroll
    for (int ks = 0; ks < 4; ++ks) {
        #pragma unroll
        for (int nt = 0; nt < 8; ++nt) {
            int byte = ((nt * 16 + l15) * 256 + (ks * 32 + hi * 8) * 2) ^ ((l15 & 7) << 4);
            short8 bfr = *(const short8*)((const char*)bt + byte);
            acc[nt] = __builtin_amdgcn_mfma_f32_16x16x32_bf16(a[ks], bfr, acc[nt], 0, 0, 0);
        }
    }

    int rowbase = blockIdx.x * 64 + w * 16 + hi * 4;
    #pragma unroll
    for (int r = 0; r < 4; ++r) {
        int ro = rowbase + r;
        if (ro < NN) {
            #pragma unroll
            for (int nt = 0; nt < 8; ++nt) {
                int col = nt * 16 + l15;
                float v = fmaxf(acc[nt][r] + bl_s[col], 0.f);
                h0[ro * 128 + col] = f2bf(v);
            }
        }
    }
}

// ---------------- dense1 + fc fused ----------------
__global__ __launch_bounds__(256) void dense1_k(
    const ushort* __restrict__ h0, const ushort* __restrict__ agg1,
    const float* __restrict__ Wl, const float* __restrict__ bl,
    const float* __restrict__ Wr,
    const float* __restrict__ Wfc, const float* __restrict__ bfc,
    float* __restrict__ out)
{
    __shared__ ushort bt[256 * 128];   // B_T[n][k] bf16, 64 KB, XOR-swizzled
    __shared__ float  bl_s[128];
    __shared__ float  wfc_s[256];

    for (int c = threadIdx.x; c < 4096; c += 256) {
        int n  = c >> 5;
        int kc = (c & 31) * 8;
        const float* wsrc = (kc < 128) ? (Wl + n * 128 + kc) : (Wr + n * 128 + (kc - 128));
        float4 f0 = *(const float4*)(wsrc);
        float4 f1 = *(const float4*)(wsrc + 4);
        short8 v;
        v[0] = f2bf(f0.x); v[1] = f2bf(f0.y); v[2] = f2bf(f0.z); v[3] = f2bf(f0.w);
        v[4] = f2bf(f1.x); v[5] = f2bf(f1.y); v[6] = f2bf(f1.z); v[7] = f2bf(f1.w);
        int byte = (n * 512 + kc * 2) ^ ((n & 7) << 4);
        *(short8*)((char*)bt + byte) = v;
    }
    if (threadIdx.x < 128) bl_s[threadIdx.x] = bl[threadIdx.x];
    if (threadIdx.x < 256) wfc_s[threadIdx.x] = Wfc[threadIdx.x];
    __syncthreads();

    int w = threadIdx.x >> 6, l = threadIdx.x & 63;
    int l15 = l & 15, hi = l >> 4;
    int row  = blockIdx.x * 64 + w * 16 + l15;
    int rowc = row < NN ? row : 0;

    short8 a[8];
    #pragma unroll
    for (int ks = 0; ks < 4; ++ks)
        a[ks] = *(const short8*)(agg1 + rowc * 128 + ks * 32 + hi * 8);
    #pragma unroll
    for (int ks = 0; ks < 4; ++ks)
        a[4 + ks] = *(const short8*)(h0 + rowc * 128 + ks * 32 + hi * 8);

    f32x4 acc[8];
    #pragma unroll
    for (int nt = 0; nt < 8; ++nt) acc[nt] = (f32x4){0.f, 0.f, 0.f, 0.f};

    #pragma unroll
    for (int ks = 0; ks < 8; ++ks) {
        #pragma unroll
        for (int nt = 0; nt < 8; ++nt) {
            int byte = ((nt * 16 + l15) * 512 + (ks * 32 + hi * 8) * 2) ^ ((l15 & 7) << 4);
            short8 bfr = *(const short8*)((const char*)bt + byte);
            acc[nt] = __builtin_amdgcn_mfma_f32_16x16x32_bf16(a[ks], bfr, acc[nt], 0, 0, 0);
        }
    }

    int rowbase = blockIdx.x * 64 + w * 16 + hi * 4;
    #pragma unroll
    for (int r = 0; r < 4; ++r) {
        float p0 = 0.f, p1 = 0.f;
        #pragma unroll
        for (int nt = 0; nt < 8; ++nt) {
            int col = nt * 16 + l15;
            float h1 = fmaxf(acc[nt][r] + bl_s[col], 0.f);
            p0 += h1 * wfc_s[col];
            p1 += h1 * wfc_s[128 + col];
        }
        p0 += __shfl_xor(p0, 1, 64); p0 += __shfl_xor(p0, 2, 64);
        p0 += __shfl_xor(p0, 4, 64); p0 += __shfl_xor(p0, 8, 64);
        p1 += __shfl_xor(p1, 1, 64); p1 += __shfl_xor(p1, 2, 64);
        p1 += __shfl_xor(p1, 4, 64); p1 += __shfl_xor(p1, 8, 64);
        int ro = rowbase + r;
        if (l15 == 0 && ro < NN) {
            float2 o; o.x = p0 + bfc[0]; o.y = p1 + bfc[1];
            *(float2*)(out + ro * 2) = o;
        }
    }
}

extern "C" void kernel_launch(void* const* d_in, const int* in_sizes, int n_in,
                              void* d_out, int out_size, void* d_ws, size_t ws_size,
                              hipStream_t stream)
{
    const float* x   = (const float*)d_in[0];
    const int*   ei  = (const int*)d_in[1];
    const float* Wl0 = (const float*)d_in[2];
    const float* bl0 = (const float*)d_in[3];
    const float* Wr0 = (const float*)d_in[4];
    const float* Wl1 = (const float*)d_in[5];
    const float* bl1 = (const float*)d_in[6];
    const float* Wr1 = (const float*)d_in[7];
    const float* Wfc = (const float*)d_in[8];
    const float* bfc = (const float*)d_in[9];
    float* out = (float*)d_out;

    const int* src = ei;
    const int* dst = ei + NE;

    // ws: deg@0 rowptr@200000 cursor@400004 nbr@600004 aggB@3800016 h0B@16600016
    //     bsum@29400016 boff@29400800
    char*   ws     = (char*)d_ws;
    int*    deg    = (int*)(ws);
    int*    rowptr = (int*)(ws + 200000);
    int*    cursor = (int*)(ws + 400004);
    int*    nbr    = (int*)(ws + 600004);
    ushort* aggB   = (ushort*)(ws + 3800016);   // agg0 (NN*64) then agg1 (NN*128)
    ushort* h0B    = (ushort*)(ws + 16600016);
    int*    bsum   = (int*)(ws + 29400016);
    int*    boff   = (int*)(ws + 29400800);

    hipMemsetAsync(deg, 0, 200000, stream);

    count_k  <<<3125, 256, 0, stream>>>(dst, deg);
    partial_k<<<NB, 256, 0, stream>>>(deg, bsum);
    scanb_k  <<<1, 256, 0, stream>>>(bsum, boff, rowptr);
    emit_k   <<<NB, 256, 0, stream>>>(deg, boff, rowptr, cursor);
    fill_k   <<<3125, 256, 0, stream>>>(src, dst, cursor, nbr);

    gather0_k<<<12500, 256, 0, stream>>>(x, rowptr, nbr, aggB);
    dense0_k <<<782, 256, 0, stream>>>(x, aggB, Wl0, bl0, Wr0, h0B);
    gather1_k<<<12500, 256, 0, stream>>>(h0B, rowptr, nbr, aggB);
    dense1_k <<<782, 256, 0, stream>>>(h0B, aggB, Wl1, bl1, Wr1, Wfc, bfc, out);
}

// Round 5
// 209.327 us; speedup vs baseline: 4.3122x; 1.3776x over previous
//
#include <hip/hip_runtime.h>
#include <hip/hip_bf16.h>

#define NN   50000
#define NE   800000
#define NB   196   // ceil(NN/256)

typedef __attribute__((ext_vector_type(8))) short short8;
typedef __attribute__((ext_vector_type(4))) float f32x4;

static __device__ __forceinline__ ushort f2bf(float f) {
    union { float f; unsigned u; } v; v.f = f;
    unsigned r = v.u + 0x7fffu + ((v.u >> 16) & 1u);   // round-to-nearest-even
    return (ushort)(r >> 16);
}
static __device__ __forceinline__ float bf2f(ushort h) {
    union { unsigned u; float f; } v; v.u = ((unsigned)h) << 16;
    return v.f;
}

// ---------------- x -> bf16 prep ----------------
__global__ __launch_bounds__(256) void cvtx_k(
    const float* __restrict__ x, ushort* __restrict__ xb)
{
    int i = blockIdx.x * 256 + threadIdx.x;     // 800,000 threads, 4 elems each
    int base = i * 4;
    if (base >= NN * 64) return;
    float4 f = *(const float4*)(x + base);
    ushort4 o;
    o.x = f2bf(f.x); o.y = f2bf(f.y); o.z = f2bf(f.z); o.w = f2bf(f.w);
    *(ushort4*)(xb + base) = o;
}

// ---------------- CSR build ----------------
__global__ __launch_bounds__(256) void count_k(
    const int* __restrict__ dst, int* __restrict__ deg)
{
    int gid = blockIdx.x * 256 + threadIdx.x;
    int stride = gridDim.x * 256;
    for (int e = gid; e < NE; e += stride)
        atomicAdd(&deg[dst[e]], 1);
}

__global__ __launch_bounds__(256) void partial_k(
    const int* __restrict__ deg, int* __restrict__ bsum)
{
    int gid = blockIdx.x * 256 + threadIdx.x;
    int v = (gid < NN) ? deg[gid] : 0;
    #pragma unroll
    for (int off = 32; off > 0; off >>= 1) v += __shfl_xor(v, off, 64);
    __shared__ int wsum[4];
    if ((threadIdx.x & 63) == 0) wsum[threadIdx.x >> 6] = v;
    __syncthreads();
    if (threadIdx.x == 0)
        bsum[blockIdx.x] = wsum[0] + wsum[1] + wsum[2] + wsum[3];
}

__global__ __launch_bounds__(256) void scanb_k(
    const int* __restrict__ bsum, int* __restrict__ boff,
    int* __restrict__ rowptr)
{
    __shared__ int s[256];
    int tid = threadIdx.x;
    int v = (tid < NB) ? bsum[tid] : 0;
    s[tid] = v;
    __syncthreads();
    for (int off = 1; off < 256; off <<= 1) {
        int add = (tid >= off) ? s[tid - off] : 0;
        __syncthreads();
        s[tid] += add;
        __syncthreads();
    }
    if (tid < NB) boff[tid] = s[tid] - v;
    if (tid == 255) rowptr[NN] = s[255];
}

__global__ __launch_bounds__(256) void emit_k(
    const int* __restrict__ deg, const int* __restrict__ boff,
    int* __restrict__ rowptr, int* __restrict__ cursor)
{
    __shared__ int s[256];
    int gid = blockIdx.x * 256 + threadIdx.x;
    int tid = threadIdx.x;
    int v = (gid < NN) ? deg[gid] : 0;
    s[tid] = v;
    __syncthreads();
    for (int off = 1; off < 256; off <<= 1) {
        int add = (tid >= off) ? s[tid - off] : 0;
        __syncthreads();
        s[tid] += add;
        __syncthreads();
    }
    if (gid < NN) {
        int excl = boff[blockIdx.x] + s[tid] - v;
        rowptr[gid] = excl;
        cursor[gid] = excl;
    }
}

__global__ __launch_bounds__(256) void fill_k(
    const int* __restrict__ src, const int* __restrict__ dst,
    int* __restrict__ cursor, int* __restrict__ nbr)
{
    int gid = blockIdx.x * 256 + threadIdx.x;
    int stride = gridDim.x * 256;
    for (int e = gid; e < NE; e += stride) {
        int d = dst[e];
        int pos = atomicAdd(&cursor[d], 1);
        nbr[pos] = src[e];
    }
}

// ---------------- gathers (mean-aggregate), 4-way MLP unroll ----------------
__global__ __launch_bounds__(256) void gather0_k(
    const ushort* __restrict__ xb, const int* __restrict__ rowptr,
    const int* __restrict__ nbr, ushort* __restrict__ agg0)
{
    int gid  = blockIdx.x * 256 + threadIdx.x;
    int lane = gid & 63;
    int node = gid >> 6;
    if (node >= NN) return;
    int b = rowptr[node], e2 = rowptr[node + 1];
    float acc = 0.f;
    int e = b;
    for (; e + 4 <= e2; e += 4) {
        int s0 = nbr[e], s1 = nbr[e + 1], s2 = nbr[e + 2], s3 = nbr[e + 3];
        ushort v0 = xb[s0 * 64 + lane];
        ushort v1 = xb[s1 * 64 + lane];
        ushort v2 = xb[s2 * 64 + lane];
        ushort v3 = xb[s3 * 64 + lane];
        acc += bf2f(v0) + bf2f(v1) + bf2f(v2) + bf2f(v3);
    }
    for (; e < e2; ++e)
        acc += bf2f(xb[nbr[e] * 64 + lane]);
    float inv = 1.0f / fmaxf((float)(e2 - b), 1.0f);
    agg0[node * 64 + lane] = f2bf(acc * inv);
}

__global__ __launch_bounds__(256) void gather1_k(
    const ushort* __restrict__ h0, const int* __restrict__ rowptr,
    const int* __restrict__ nbr, ushort* __restrict__ agg1)
{
    int gid  = blockIdx.x * 256 + threadIdx.x;
    int lane = gid & 63;
    int node = gid >> 6;
    if (node >= NN) return;
    int b = rowptr[node], e2 = rowptr[node + 1];
    const unsigned* h2 = (const unsigned*)h0;   // 2 bf16 per load
    float a0 = 0.f, a1 = 0.f;
    int e = b;
    for (; e + 4 <= e2; e += 4) {
        int s0 = nbr[e], s1 = nbr[e + 1], s2 = nbr[e + 2], s3 = nbr[e + 3];
        unsigned v0 = h2[s0 * 64 + lane];
        unsigned v1 = h2[s1 * 64 + lane];
        unsigned v2 = h2[s2 * 64 + lane];
        unsigned v3 = h2[s3 * 64 + lane];
        a0 += bf2f((ushort)(v0 & 0xffffu)) + bf2f((ushort)(v1 & 0xffffu))
            + bf2f((ushort)(v2 & 0xffffu)) + bf2f((ushort)(v3 & 0xffffu));
        a1 += bf2f((ushort)(v0 >> 16)) + bf2f((ushort)(v1 >> 16))
            + bf2f((ushort)(v2 >> 16)) + bf2f((ushort)(v3 >> 16));
    }
    for (; e < e2; ++e) {
        unsigned v = h2[nbr[e] * 64 + lane];
        a0 += bf2f((ushort)(v & 0xffffu));
        a1 += bf2f((ushort)(v >> 16));
    }
    float inv = 1.0f / fmaxf((float)(e2 - b), 1.0f);
    unsigned o = (unsigned)f2bf(a0 * inv) | ((unsigned)f2bf(a1 * inv) << 16);
    ((unsigned*)agg1)[node * 64 + lane] = o;
}

// ---------------- dense0: h0 = relu([agg0|x] @ [Wl0;Wr0]^T + bl0), MFMA ----------------
__global__ __launch_bounds__(256) void dense0_k(
    const ushort* __restrict__ xb, const ushort* __restrict__ agg0,
    const float* __restrict__ Wl, const float* __restrict__ bl,
    const float* __restrict__ Wr, ushort* __restrict__ h0)
{
    __shared__ ushort bt[128 * 128];   // B_T[n][k] bf16, XOR-swizzled, 32 KB
    __shared__ float  bl_s[128];

    for (int c = threadIdx.x; c < 2048; c += 256) {
        int n  = c >> 4;
        int kc = (c & 15) * 8;
        const float* wsrc = (kc < 64) ? (Wl + n * 64 + kc) : (Wr + n * 64 + (kc - 64));
        float4 f0 = *(const float4*)(wsrc);
        float4 f1 = *(const float4*)(wsrc + 4);
        short8 v;
        v[0] = f2bf(f0.x); v[1] = f2bf(f0.y); v[2] = f2bf(f0.z); v[3] = f2bf(f0.w);
        v[4] = f2bf(f1.x); v[5] = f2bf(f1.y); v[6] = f2bf(f1.z); v[7] = f2bf(f1.w);
        int byte = (n * 256 + kc * 2) ^ ((n & 7) << 4);
        *(short8*)((char*)bt + byte) = v;
    }
    if (threadIdx.x < 128) bl_s[threadIdx.x] = bl[threadIdx.x];
    __syncthreads();

    int w = threadIdx.x >> 6, l = threadIdx.x & 63;
    int l15 = l & 15, hi = l >> 4;
    int row  = blockIdx.x * 64 + w * 16 + l15;
    int rowc = row < NN ? row : 0;

    short8 a[4];
    a[0] = *(const short8*)(agg0 + rowc * 64 + hi * 8);
    a[1] = *(const short8*)(agg0 + rowc * 64 + 32 + hi * 8);
    a[2] = *(const short8*)(xb + rowc * 64 + hi * 8);
    a[3] = *(const short8*)(xb + rowc * 64 + 32 + hi * 8);

    f32x4 acc[8];
    #pragma unroll
    for (int nt = 0; nt < 8; ++nt) acc[nt] = (f32x4){0.f, 0.f, 0.f, 0.f};

    #pragma unroll
    for (int ks = 0; ks < 4; ++ks) {
        #pragma unroll
        for (int nt = 0; nt < 8; ++nt) {
            int byte = ((nt * 16 + l15) * 256 + (ks * 32 + hi * 8) * 2) ^ ((l15 & 7) << 4);
            short8 bfr = *(const short8*)((const char*)bt + byte);
            acc[nt] = __builtin_amdgcn_mfma_f32_16x16x32_bf16(a[ks], bfr, acc[nt], 0, 0, 0);
        }
    }

    int rowbase = blockIdx.x * 64 + w * 16 + hi * 4;
    #pragma unroll
    for (int r = 0; r < 4; ++r) {
        int ro = rowbase + r;
        if (ro < NN) {
            #pragma unroll
            for (int nt = 0; nt < 8; ++nt) {
                int col = nt * 16 + l15;
                float v = fmaxf(acc[nt][r] + bl_s[col], 0.f);
                h0[ro * 128 + col] = f2bf(v);
            }
        }
    }
}

// ---------------- dense1 + fc fused ----------------
__global__ __launch_bounds__(256) void dense1_k(
    const ushort* __restrict__ h0, const ushort* __restrict__ agg1,
    const float* __restrict__ Wl, const float* __restrict__ bl,
    const float* __restrict__ Wr,
    const float* __restrict__ Wfc, const float* __restrict__ bfc,
    float* __restrict__ out)
{
    __shared__ ushort bt[256 * 128];   // B_T[n][k] bf16, 64 KB, XOR-swizzled
    __shared__ float  bl_s[128];
    __shared__ float  wfc_s[256];

    for (int c = threadIdx.x; c < 4096; c += 256) {
        int n  = c >> 5;
        int kc = (c & 31) * 8;
        const float* wsrc = (kc < 128) ? (Wl + n * 128 + kc) : (Wr + n * 128 + (kc - 128));
        float4 f0 = *(const float4*)(wsrc);
        float4 f1 = *(const float4*)(wsrc + 4);
        short8 v;
        v[0] = f2bf(f0.x); v[1] = f2bf(f0.y); v[2] = f2bf(f0.z); v[3] = f2bf(f0.w);
        v[4] = f2bf(f1.x); v[5] = f2bf(f1.y); v[6] = f2bf(f1.z); v[7] = f2bf(f1.w);
        int byte = (n * 512 + kc * 2) ^ ((n & 7) << 4);
        *(short8*)((char*)bt + byte) = v;
    }
    if (threadIdx.x < 128) bl_s[threadIdx.x] = bl[threadIdx.x];
    if (threadIdx.x < 256) wfc_s[threadIdx.x] = Wfc[threadIdx.x];
    __syncthreads();

    int w = threadIdx.x >> 6, l = threadIdx.x & 63;
    int l15 = l & 15, hi = l >> 4;
    int row  = blockIdx.x * 64 + w * 16 + l15;
    int rowc = row < NN ? row : 0;

    short8 a[8];
    #pragma unroll
    for (int ks = 0; ks < 4; ++ks)
        a[ks] = *(const short8*)(agg1 + rowc * 128 + ks * 32 + hi * 8);
    #pragma unroll
    for (int ks = 0; ks < 4; ++ks)
        a[4 + ks] = *(const short8*)(h0 + rowc * 128 + ks * 32 + hi * 8);

    f32x4 acc[8];
    #pragma unroll
    for (int nt = 0; nt < 8; ++nt) acc[nt] = (f32x4){0.f, 0.f, 0.f, 0.f};

    #pragma unroll
    for (int ks = 0; ks < 8; ++ks) {
        #pragma unroll
        for (int nt = 0; nt < 8; ++nt) {
            int byte = ((nt * 16 + l15) * 512 + (ks * 32 + hi * 8) * 2) ^ ((l15 & 7) << 4);
            short8 bfr = *(const short8*)((const char*)bt + byte);
            acc[nt] = __builtin_amdgcn_mfma_f32_16x16x32_bf16(a[ks], bfr, acc[nt], 0, 0, 0);
        }
    }

    int rowbase = blockIdx.x * 64 + w * 16 + hi * 4;
    #pragma unroll
    for (int r = 0; r < 4; ++r) {
        float p0 = 0.f, p1 = 0.f;
        #pragma unroll
        for (int nt = 0; nt < 8; ++nt) {
            int col = nt * 16 + l15;
            float h1 = fmaxf(acc[nt][r] + bl_s[col], 0.f);
            p0 += h1 * wfc_s[col];
            p1 += h1 * wfc_s[128 + col];
        }
        p0 += __shfl_xor(p0, 1, 64); p0 += __shfl_xor(p0, 2, 64);
        p0 += __shfl_xor(p0, 4, 64); p0 += __shfl_xor(p0, 8, 64);
        p1 += __shfl_xor(p1, 1, 64); p1 += __shfl_xor(p1, 2, 64);
        p1 += __shfl_xor(p1, 4, 64); p1 += __shfl_xor(p1, 8, 64);
        int ro = rowbase + r;
        if (l15 == 0 && ro < NN) {
            float2 o; o.x = p0 + bfc[0]; o.y = p1 + bfc[1];
            *(float2*)(out + ro * 2) = o;
        }
    }
}

extern "C" void kernel_launch(void* const* d_in, const int* in_sizes, int n_in,
                              void* d_out, int out_size, void* d_ws, size_t ws_size,
                              hipStream_t stream)
{
    const float* x   = (const float*)d_in[0];
    const int*   ei  = (const int*)d_in[1];
    const float* Wl0 = (const float*)d_in[2];
    const float* bl0 = (const float*)d_in[3];
    const float* Wr0 = (const float*)d_in[4];
    const float* Wl1 = (const float*)d_in[5];
    const float* bl1 = (const float*)d_in[6];
    const float* Wr1 = (const float*)d_in[7];
    const float* Wfc = (const float*)d_in[8];
    const float* bfc = (const float*)d_in[9];
    float* out = (float*)d_out;

    const int* src = ei;
    const int* dst = ei + NE;

    // ws: deg@0 rowptr@200000 cursor@400004 nbr@600004 aggB@3800016 h0B@16600016
    //     bsum@29400016 boff@29400800 xb@29401600
    char*   ws     = (char*)d_ws;
    int*    deg    = (int*)(ws);
    int*    rowptr = (int*)(ws + 200000);
    int*    cursor = (int*)(ws + 400004);
    int*    nbr    = (int*)(ws + 600004);
    ushort* aggB   = (ushort*)(ws + 3800016);   // agg0 (NN*64) then agg1 (NN*128)
    ushort* h0B    = (ushort*)(ws + 16600016);
    int*    bsum   = (int*)(ws + 29400016);
    int*    boff   = (int*)(ws + 29400800);
    ushort* xb     = (ushort*)(ws + 29401600);  // 6.4 MB

    hipMemsetAsync(deg, 0, 200000, stream);

    cvtx_k   <<<3125, 256, 0, stream>>>(x, xb);
    count_k  <<<3125, 256, 0, stream>>>(dst, deg);
    partial_k<<<NB, 256, 0, stream>>>(deg, bsum);
    scanb_k  <<<1, 256, 0, stream>>>(bsum, boff, rowptr);
    emit_k   <<<NB, 256, 0, stream>>>(deg, boff, rowptr, cursor);
    fill_k   <<<3125, 256, 0, stream>>>(src, dst, cursor, nbr);

    gather0_k<<<12500, 256, 0, stream>>>(xb, rowptr, nbr, aggB);
    dense0_k <<<782, 256, 0, stream>>>(xb, aggB, Wl0, bl0, Wr0, h0B);
    gather1_k<<<12500, 256, 0, stream>>>(h0B, rowptr, nbr, aggB);
    dense1_k <<<782, 256, 0, stream>>>(h0B, aggB, Wl1, bl1, Wr1, Wfc, bfc, out);
}

// Round 6
// 167.844 us; speedup vs baseline: 5.3779x; 1.2472x over previous
//
#include <hip/hip_runtime.h>
#include <hip/hip_bf16.h>

#define NN   50000
#define NE   800000
#define NB   196   // ceil(NN/256)

typedef __attribute__((ext_vector_type(8))) short short8;
typedef __attribute__((ext_vector_type(4))) float f32x4;

static __device__ __forceinline__ ushort f2bf(float f) {
    union { float f; unsigned u; } v; v.f = f;
    unsigned r = v.u + 0x7fffu + ((v.u >> 16) & 1u);   // round-to-nearest-even
    return (ushort)(r >> 16);
}
static __device__ __forceinline__ float bf2f(ushort h) {
    union { unsigned u; float f; } v; v.u = ((unsigned)h) << 16;
    return v.f;
}

// ---------------- count (+rank) fused with x->bf16 convert ----------------
// NE == 3125*256 threads exactly; each thread: 1 edge + 4 x-elements.
__global__ __launch_bounds__(256) void count_k(
    const int* __restrict__ dst, int* __restrict__ deg,
    int* __restrict__ rank,
    const float* __restrict__ x, ushort* __restrict__ xb)
{
    int gid = blockIdx.x * 256 + threadIdx.x;
    // cvtx part (independent streaming work overlaps atomic latency)
    int base = gid * 4;
    float4 f = *(const float4*)(x + base);
    ushort4 o;
    o.x = f2bf(f.x); o.y = f2bf(f.y); o.z = f2bf(f.z); o.w = f2bf(f.w);
    *(ushort4*)(xb + base) = o;
    // count part: rank = old count (coalesced store indexed by edge)
    int d = dst[gid];
    rank[gid] = atomicAdd(&deg[d], 1);
}

__global__ __launch_bounds__(256) void partial_k(
    const int* __restrict__ deg, int* __restrict__ bsum)
{
    int gid = blockIdx.x * 256 + threadIdx.x;
    int v = (gid < NN) ? deg[gid] : 0;
    #pragma unroll
    for (int off = 32; off > 0; off >>= 1) v += __shfl_xor(v, off, 64);
    __shared__ int wsum[4];
    if ((threadIdx.x & 63) == 0) wsum[threadIdx.x >> 6] = v;
    __syncthreads();
    if (threadIdx.x == 0)
        bsum[blockIdx.x] = wsum[0] + wsum[1] + wsum[2] + wsum[3];
}

__global__ __launch_bounds__(256) void scanb_k(
    const int* __restrict__ bsum, int* __restrict__ boff,
    int* __restrict__ rowptr)
{
    __shared__ int s[256];
    int tid = threadIdx.x;
    int v = (tid < NB) ? bsum[tid] : 0;
    s[tid] = v;
    __syncthreads();
    for (int off = 1; off < 256; off <<= 1) {
        int add = (tid >= off) ? s[tid - off] : 0;
        __syncthreads();
        s[tid] += add;
        __syncthreads();
    }
    if (tid < NB) boff[tid] = s[tid] - v;
    if (tid == 255) rowptr[NN] = s[255];
}

__global__ __launch_bounds__(256) void emit_k(
    const int* __restrict__ deg, const int* __restrict__ boff,
    int* __restrict__ rowptr)
{
    __shared__ int s[256];
    int gid = blockIdx.x * 256 + threadIdx.x;
    int tid = threadIdx.x;
    int v = (gid < NN) ? deg[gid] : 0;
    s[tid] = v;
    __syncthreads();
    for (int off = 1; off < 256; off <<= 1) {
        int add = (tid >= off) ? s[tid - off] : 0;
        __syncthreads();
        s[tid] += add;
        __syncthreads();
    }
    if (gid < NN)
        rowptr[gid] = boff[blockIdx.x] + s[tid] - v;
}

// deterministic fill: position = rowptr[dst] + rank, no atomics
__global__ __launch_bounds__(256) void fill_k(
    const int* __restrict__ src, const int* __restrict__ dst,
    const int* __restrict__ rowptr, const int* __restrict__ rank,
    int* __restrict__ nbr)
{
    int e = blockIdx.x * 256 + threadIdx.x;
    int d = dst[e];
    nbr[rowptr[d] + rank[e]] = src[e];
}

// ---------------- gathers (mean-aggregate), 4-way MLP unroll ----------------
__global__ __launch_bounds__(256) void gather0_k(
    const ushort* __restrict__ xb, const int* __restrict__ rowptr,
    const int* __restrict__ nbr, ushort* __restrict__ agg0)
{
    int gid  = blockIdx.x * 256 + threadIdx.x;
    int lane = gid & 63;
    int node = gid >> 6;
    if (node >= NN) return;
    int b = rowptr[node], e2 = rowptr[node + 1];
    float acc = 0.f;
    int e = b;
    for (; e + 4 <= e2; e += 4) {
        int s0 = nbr[e], s1 = nbr[e + 1], s2 = nbr[e + 2], s3 = nbr[e + 3];
        ushort v0 = xb[s0 * 64 + lane];
        ushort v1 = xb[s1 * 64 + lane];
        ushort v2 = xb[s2 * 64 + lane];
        ushort v3 = xb[s3 * 64 + lane];
        acc += bf2f(v0) + bf2f(v1) + bf2f(v2) + bf2f(v3);
    }
    for (; e < e2; ++e)
        acc += bf2f(xb[nbr[e] * 64 + lane]);
    float inv = 1.0f / fmaxf((float)(e2 - b), 1.0f);
    agg0[node * 64 + lane] = f2bf(acc * inv);
}

__global__ __launch_bounds__(256) void gather1_k(
    const ushort* __restrict__ h0, const int* __restrict__ rowptr,
    const int* __restrict__ nbr, ushort* __restrict__ agg1)
{
    int gid  = blockIdx.x * 256 + threadIdx.x;
    int lane = gid & 63;
    int node = gid >> 6;
    if (node >= NN) return;
    int b = rowptr[node], e2 = rowptr[node + 1];
    const unsigned* h2 = (const unsigned*)h0;   // 2 bf16 per load
    float a0 = 0.f, a1 = 0.f;
    int e = b;
    for (; e + 4 <= e2; e += 4) {
        int s0 = nbr[e], s1 = nbr[e + 1], s2 = nbr[e + 2], s3 = nbr[e + 3];
        unsigned v0 = h2[s0 * 64 + lane];
        unsigned v1 = h2[s1 * 64 + lane];
        unsigned v2 = h2[s2 * 64 + lane];
        unsigned v3 = h2[s3 * 64 + lane];
        a0 += bf2f((ushort)(v0 & 0xffffu)) + bf2f((ushort)(v1 & 0xffffu))
            + bf2f((ushort)(v2 & 0xffffu)) + bf2f((ushort)(v3 & 0xffffu));
        a1 += bf2f((ushort)(v0 >> 16)) + bf2f((ushort)(v1 >> 16))
            + bf2f((ushort)(v2 >> 16)) + bf2f((ushort)(v3 >> 16));
    }
    for (; e < e2; ++e) {
        unsigned v = h2[nbr[e] * 64 + lane];
        a0 += bf2f((ushort)(v & 0xffffu));
        a1 += bf2f((ushort)(v >> 16));
    }
    float inv = 1.0f / fmaxf((float)(e2 - b), 1.0f);
    unsigned o = (unsigned)f2bf(a0 * inv) | ((unsigned)f2bf(a1 * inv) << 16);
    ((unsigned*)agg1)[node * 64 + lane] = o;
}

// ---------------- dense0: h0 = relu([agg0|x] @ [Wl0;Wr0]^T + bl0), MFMA ----------------
__global__ __launch_bounds__(256) void dense0_k(
    const ushort* __restrict__ xb, const ushort* __restrict__ agg0,
    const float* __restrict__ Wl, const float* __restrict__ bl,
    const float* __restrict__ Wr, ushort* __restrict__ h0)
{
    __shared__ ushort bt[128 * 128];   // B_T[n][k] bf16, XOR-swizzled, 32 KB
    __shared__ float  bl_s[128];

    for (int c = threadIdx.x; c < 2048; c += 256) {
        int n  = c >> 4;
        int kc = (c & 15) * 8;
        const float* wsrc = (kc < 64) ? (Wl + n * 64 + kc) : (Wr + n * 64 + (kc - 64));
        float4 f0 = *(const float4*)(wsrc);
        float4 f1 = *(const float4*)(wsrc + 4);
        short8 v;
        v[0] = f2bf(f0.x); v[1] = f2bf(f0.y); v[2] = f2bf(f0.z); v[3] = f2bf(f0.w);
        v[4] = f2bf(f1.x); v[5] = f2bf(f1.y); v[6] = f2bf(f1.z); v[7] = f2bf(f1.w);
        int byte = (n * 256 + kc * 2) ^ ((n & 7) << 4);
        *(short8*)((char*)bt + byte) = v;
    }
    if (threadIdx.x < 128) bl_s[threadIdx.x] = bl[threadIdx.x];
    __syncthreads();

    int w = threadIdx.x >> 6, l = threadIdx.x & 63;
    int l15 = l & 15, hi = l >> 4;
    int row  = blockIdx.x * 64 + w * 16 + l15;
    int rowc = row < NN ? row : 0;

    short8 a[4];
    a[0] = *(const short8*)(agg0 + rowc * 64 + hi * 8);
    a[1] = *(const short8*)(agg0 + rowc * 64 + 32 + hi * 8);
    a[2] = *(const short8*)(xb + rowc * 64 + hi * 8);
    a[3] = *(const short8*)(xb + rowc * 64 + 32 + hi * 8);

    f32x4 acc[8];
    #pragma unroll
    for (int nt = 0; nt < 8; ++nt) acc[nt] = (f32x4){0.f, 0.f, 0.f, 0.f};

    #pragma unroll
    for (int ks = 0; ks < 4; ++ks) {
        #pragma unroll
        for (int nt = 0; nt < 8; ++nt) {
            int byte = ((nt * 16 + l15) * 256 + (ks * 32 + hi * 8) * 2) ^ ((l15 & 7) << 4);
            short8 bfr = *(const short8*)((const char*)bt + byte);
            acc[nt] = __builtin_amdgcn_mfma_f32_16x16x32_bf16(a[ks], bfr, acc[nt], 0, 0, 0);
        }
    }

    int rowbase = blockIdx.x * 64 + w * 16 + hi * 4;
    #pragma unroll
    for (int r = 0; r < 4; ++r) {
        int ro = rowbase + r;
        if (ro < NN) {
            #pragma unroll
            for (int nt = 0; nt < 8; ++nt) {
                int col = nt * 16 + l15;
                float v = fmaxf(acc[nt][r] + bl_s[col], 0.f);
                h0[ro * 128 + col] = f2bf(v);
            }
        }
    }
}

// ---------------- dense1 + fc fused ----------------
__global__ __launch_bounds__(256) void dense1_k(
    const ushort* __restrict__ h0, const ushort* __restrict__ agg1,
    const float* __restrict__ Wl, const float* __restrict__ bl,
    const float* __restrict__ Wr,
    const float* __restrict__ Wfc, const float* __restrict__ bfc,
    float* __restrict__ out)
{
    __shared__ ushort bt[256 * 128];   // B_T[n][k] bf16, 64 KB, XOR-swizzled
    __shared__ float  bl_s[128];
    __shared__ float  wfc_s[256];

    for (int c = threadIdx.x; c < 4096; c += 256) {
        int n  = c >> 5;
        int kc = (c & 31) * 8;
        const float* wsrc = (kc < 128) ? (Wl + n * 128 + kc) : (Wr + n * 128 + (kc - 128));
        float4 f0 = *(const float4*)(wsrc);
        float4 f1 = *(const float4*)(wsrc + 4);
        short8 v;
        v[0] = f2bf(f0.x); v[1] = f2bf(f0.y); v[2] = f2bf(f0.z); v[3] = f2bf(f0.w);
        v[4] = f2bf(f1.x); v[5] = f2bf(f1.y); v[6] = f2bf(f1.z); v[7] = f2bf(f1.w);
        int byte = (n * 512 + kc * 2) ^ ((n & 7) << 4);
        *(short8*)((char*)bt + byte) = v;
    }
    if (threadIdx.x < 128) bl_s[threadIdx.x] = bl[threadIdx.x];
    if (threadIdx.x < 256) wfc_s[threadIdx.x] = Wfc[threadIdx.x];
    __syncthreads();

    int w = threadIdx.x >> 6, l = threadIdx.x & 63;
    int l15 = l & 15, hi = l >> 4;
    int row  = blockIdx.x * 64 + w * 16 + l15;
    int rowc = row < NN ? row : 0;

    short8 a[8];
    #pragma unroll
    for (int ks = 0; ks < 4; ++ks)
        a[ks] = *(const short8*)(agg1 + rowc * 128 + ks * 32 + hi * 8);
    #pragma unroll
    for (int ks = 0; ks < 4; ++ks)
        a[4 + ks] = *(const short8*)(h0 + rowc * 128 + ks * 32 + hi * 8);

    f32x4 acc[8];
    #pragma unroll
    for (int nt = 0; nt < 8; ++nt) acc[nt] = (f32x4){0.f, 0.f, 0.f, 0.f};

    #pragma unroll
    for (int ks = 0; ks < 8; ++ks) {
        #pragma unroll
        for (int nt = 0; nt < 8; ++nt) {
            int byte = ((nt * 16 + l15) * 512 + (ks * 32 + hi * 8) * 2) ^ ((l15 & 7) << 4);
            short8 bfr = *(const short8*)((const char*)bt + byte);
            acc[nt] = __builtin_amdgcn_mfma_f32_16x16x32_bf16(a[ks], bfr, acc[nt], 0, 0, 0);
        }
    }

    int rowbase = blockIdx.x * 64 + w * 16 + hi * 4;
    #pragma unroll
    for (int r = 0; r < 4; ++r) {
        float p0 = 0.f, p1 = 0.f;
        #pragma unroll
        for (int nt = 0; nt < 8; ++nt) {
            int col = nt * 16 + l15;
            float h1 = fmaxf(acc[nt][r] + bl_s[col], 0.f);
            p0 += h1 * wfc_s[col];
            p1 += h1 * wfc_s[128 + col];
        }
        p0 += __shfl_xor(p0, 1, 64); p0 += __shfl_xor(p0, 2, 64);
        p0 += __shfl_xor(p0, 4, 64); p0 += __shfl_xor(p0, 8, 64);
        p1 += __shfl_xor(p1, 1, 64); p1 += __shfl_xor(p1, 2, 64);
        p1 += __shfl_xor(p1, 4, 64); p1 += __shfl_xor(p1, 8, 64);
        int ro = rowbase + r;
        if (l15 == 0 && ro < NN) {
            float2 o; o.x = p0 + bfc[0]; o.y = p1 + bfc[1];
            *(float2*)(out + ro * 2) = o;
        }
    }
}

extern "C" void kernel_launch(void* const* d_in, const int* in_sizes, int n_in,
                              void* d_out, int out_size, void* d_ws, size_t ws_size,
                              hipStream_t stream)
{
    const float* x   = (const float*)d_in[0];
    const int*   ei  = (const int*)d_in[1];
    const float* Wl0 = (const float*)d_in[2];
    const float* bl0 = (const float*)d_in[3];
    const float* Wr0 = (const float*)d_in[4];
    const float* Wl1 = (const float*)d_in[5];
    const float* bl1 = (const float*)d_in[6];
    const float* Wr1 = (const float*)d_in[7];
    const float* Wfc = (const float*)d_in[8];
    const float* bfc = (const float*)d_in[9];
    float* out = (float*)d_out;

    const int* src = ei;
    const int* dst = ei + NE;

    // ws layout (bytes):
    //   deg    @ 0          (200,000)   <- memset
    //   rowptr @ 200,000    (200,004)
    //   rank   @ 400,004    (3,200,000)
    //   nbr    @ 3,600,004  (3,200,000)
    //   aggB   @ 6,800,016  (12,800,000)  agg0 (NN*64*2B) / agg1 (NN*128*2B) share
    //   h0B    @ 19,600,016 (12,800,000)
    //   bsum   @ 32,400,016 (784)
    //   boff   @ 32,400,800 (784)
    //   xb     @ 32,401,600 (6,400,000)
    char*   ws     = (char*)d_ws;
    int*    deg    = (int*)(ws);
    int*    rowptr = (int*)(ws + 200000);
    int*    rank   = (int*)(ws + 400004);
    int*    nbr    = (int*)(ws + 3600004);
    ushort* aggB   = (ushort*)(ws + 6800016);
    ushort* h0B    = (ushort*)(ws + 19600016);
    int*    bsum   = (int*)(ws + 32400016);
    int*    boff   = (int*)(ws + 32400800);
    ushort* xb     = (ushort*)(ws + 32401600);

    hipMemsetAsync(deg, 0, 200000, stream);

    count_k  <<<3125, 256, 0, stream>>>(dst, deg, rank, x, xb);
    partial_k<<<NB, 256, 0, stream>>>(deg, bsum);
    scanb_k  <<<1, 256, 0, stream>>>(bsum, boff, rowptr);
    emit_k   <<<NB, 256, 0, stream>>>(deg, boff, rowptr);
    fill_k   <<<3125, 256, 0, stream>>>(src, dst, rowptr, rank, nbr);

    gather0_k<<<12500, 256, 0, stream>>>(xb, rowptr, nbr, aggB);
    dense0_k <<<782, 256, 0, stream>>>(xb, aggB, Wl0, bl0, Wr0, h0B);
    gather1_k<<<12500, 256, 0, stream>>>(h0B, rowptr, nbr, aggB);
    dense1_k <<<782, 256, 0, stream>>>(h0B, aggB, Wl1, bl1, Wr1, Wfc, bfc, out);
}

// Round 7
// 148.750 us; speedup vs baseline: 6.0683x; 1.1284x over previous
//
#include <hip/hip_runtime.h>
#include <hip/hip_bf16.h>

#define NN   50000
#define NE   800000
#define NB   196   // ceil(NN/256)

typedef __attribute__((ext_vector_type(8))) short short8;
typedef __attribute__((ext_vector_type(4))) float f32x4;

static __device__ __forceinline__ ushort f2bf(float f) {
    union { float f; unsigned u; } v; v.f = f;
    unsigned r = v.u + 0x7fffu + ((v.u >> 16) & 1u);   // round-to-nearest-even
    return (ushort)(r >> 16);
}
static __device__ __forceinline__ float bf2f(ushort h) {
    union { unsigned u; float f; } v; v.u = ((unsigned)h) << 16;
    return v.f;
}

// ---------------- count (+rank) + x->bf16 + weight-image prep ----------------
// NE == 3125*256 threads exactly; each thread: 1 edge + 4 x-elements.
// Threads gid<2048 additionally bake the swizzled bf16 weight LDS-images.
__global__ __launch_bounds__(256) void count_k(
    const int* __restrict__ dst, int* __restrict__ deg,
    int* __restrict__ rank,
    const float* __restrict__ x, ushort* __restrict__ xb,
    const float* __restrict__ Wl0, const float* __restrict__ Wr0,
    const float* __restrict__ Wl1, const float* __restrict__ Wr1,
    ushort* __restrict__ wbt0, ushort* __restrict__ wbt1)
{
    int gid = blockIdx.x * 256 + threadIdx.x;

    // weight-image prep (identical byte layout to dense kernels' LDS reads)
    if (gid < 2048) {
        {   // dense0 image: [n=128][k=128] bf16, 2048 chunks of 8
            int c = gid;
            int n  = c >> 4;
            int kc = (c & 15) * 8;
            const float* wsrc = (kc < 64) ? (Wl0 + n * 64 + kc) : (Wr0 + n * 64 + (kc - 64));
            float4 f0 = *(const float4*)(wsrc);
            float4 f1 = *(const float4*)(wsrc + 4);
            short8 v;
            v[0] = f2bf(f0.x); v[1] = f2bf(f0.y); v[2] = f2bf(f0.z); v[3] = f2bf(f0.w);
            v[4] = f2bf(f1.x); v[5] = f2bf(f1.y); v[6] = f2bf(f1.z); v[7] = f2bf(f1.w);
            int byte = (n * 256 + kc * 2) ^ ((n & 7) << 4);
            *(short8*)((char*)wbt0 + byte) = v;
        }
        #pragma unroll
        for (int rep = 0; rep < 2; ++rep) {   // dense1 image: 4096 chunks
            int c = gid + rep * 2048;
            int n  = c >> 5;
            int kc = (c & 31) * 8;
            const float* wsrc = (kc < 128) ? (Wl1 + n * 128 + kc) : (Wr1 + n * 128 + (kc - 128));
            float4 f0 = *(const float4*)(wsrc);
            float4 f1 = *(const float4*)(wsrc + 4);
            short8 v;
            v[0] = f2bf(f0.x); v[1] = f2bf(f0.y); v[2] = f2bf(f0.z); v[3] = f2bf(f0.w);
            v[4] = f2bf(f1.x); v[5] = f2bf(f1.y); v[6] = f2bf(f1.z); v[7] = f2bf(f1.w);
            int byte = (n * 512 + kc * 2) ^ ((n & 7) << 4);
            *(short8*)((char*)wbt1 + byte) = v;
        }
    }

    // cvtx part (independent streaming work overlaps atomic latency)
    int base = gid * 4;
    float4 f = *(const float4*)(x + base);
    ushort4 o;
    o.x = f2bf(f.x); o.y = f2bf(f.y); o.z = f2bf(f.z); o.w = f2bf(f.w);
    *(ushort4*)(xb + base) = o;
    // count part: rank = old count (coalesced store indexed by edge)
    int d = dst[gid];
    rank[gid] = atomicAdd(&deg[d], 1);
}

__global__ __launch_bounds__(256) void partial_k(
    const int* __restrict__ deg, int* __restrict__ bsum)
{
    int gid = blockIdx.x * 256 + threadIdx.x;
    int v = (gid < NN) ? deg[gid] : 0;
    #pragma unroll
    for (int off = 32; off > 0; off >>= 1) v += __shfl_xor(v, off, 64);
    __shared__ int wsum[4];
    if ((threadIdx.x & 63) == 0) wsum[threadIdx.x >> 6] = v;
    __syncthreads();
    if (threadIdx.x == 0)
        bsum[blockIdx.x] = wsum[0] + wsum[1] + wsum[2] + wsum[3];
}

// emit: per-chunk exclusive scan of deg, plus in-block scan of the 196 bsums
__global__ __launch_bounds__(256) void emit_k(
    const int* __restrict__ deg, const int* __restrict__ bsum,
    int* __restrict__ rowptr)
{
    __shared__ int s[256], sb[256];
    int tid = threadIdx.x;
    int gid = blockIdx.x * 256 + tid;
    int v  = (gid < NN) ? deg[gid] : 0;
    int bv = (tid < NB) ? bsum[tid] : 0;
    s[tid] = v; sb[tid] = bv;
    __syncthreads();
    for (int off = 1; off < 256; off <<= 1) {
        int a1 = (tid >= off) ? s[tid - off] : 0;
        int a2 = (tid >= off) ? sb[tid - off] : 0;
        __syncthreads();
        s[tid] += a1; sb[tid] += a2;
        __syncthreads();
    }
    int boff = (blockIdx.x == 0) ? 0 : sb[blockIdx.x - 1];
    if (gid < NN) rowptr[gid] = boff + s[tid] - v;
    if (blockIdx.x == 0 && tid == 0) rowptr[NN] = NE;
}

// deterministic fill: position = rowptr[dst] + rank, no atomics
__global__ __launch_bounds__(256) void fill_k(
    const int* __restrict__ src, const int* __restrict__ dst,
    const int* __restrict__ rowptr, const int* __restrict__ rank,
    int* __restrict__ nbr)
{
    int e = blockIdx.x * 256 + threadIdx.x;
    int d = dst[e];
    nbr[rowptr[d] + rank[e]] = src[e];
}

// ---------------- gathers (mean-aggregate), 8-way MLP unroll ----------------
__global__ __launch_bounds__(256) void gather0_k(
    const ushort* __restrict__ xb, const int* __restrict__ rowptr,
    const int* __restrict__ nbr, ushort* __restrict__ agg0)
{
    int gid  = blockIdx.x * 256 + threadIdx.x;
    int lane = gid & 63;
    int node = gid >> 6;
    if (node >= NN) return;
    int b = rowptr[node], e2 = rowptr[node + 1];
    float acc = 0.f;
    int e = b;
    for (; e + 8 <= e2; e += 8) {
        int s0 = nbr[e],     s1 = nbr[e + 1], s2 = nbr[e + 2], s3 = nbr[e + 3];
        int s4 = nbr[e + 4], s5 = nbr[e + 5], s6 = nbr[e + 6], s7 = nbr[e + 7];
        float t0 = bf2f(xb[s0 * 64 + lane]);
        float t1 = bf2f(xb[s1 * 64 + lane]);
        float t2 = bf2f(xb[s2 * 64 + lane]);
        float t3 = bf2f(xb[s3 * 64 + lane]);
        float t4 = bf2f(xb[s4 * 64 + lane]);
        float t5 = bf2f(xb[s5 * 64 + lane]);
        float t6 = bf2f(xb[s6 * 64 + lane]);
        float t7 = bf2f(xb[s7 * 64 + lane]);
        acc += ((t0 + t1) + (t2 + t3)) + ((t4 + t5) + (t6 + t7));
    }
    for (; e + 2 <= e2; e += 2) {
        int s0 = nbr[e], s1 = nbr[e + 1];
        acc += bf2f(xb[s0 * 64 + lane]) + bf2f(xb[s1 * 64 + lane]);
    }
    if (e < e2)
        acc += bf2f(xb[nbr[e] * 64 + lane]);
    float inv = 1.0f / fmaxf((float)(e2 - b), 1.0f);
    agg0[node * 64 + lane] = f2bf(acc * inv);
}

__global__ __launch_bounds__(256) void gather1_k(
    const ushort* __restrict__ h0, const int* __restrict__ rowptr,
    const int* __restrict__ nbr, ushort* __restrict__ agg1)
{
    int gid  = blockIdx.x * 256 + threadIdx.x;
    int lane = gid & 63;
    int node = gid >> 6;
    if (node >= NN) return;
    int b = rowptr[node], e2 = rowptr[node + 1];
    const unsigned* h2 = (const unsigned*)h0;   // 2 bf16 per load
    float a0 = 0.f, a1 = 0.f;
    int e = b;
    for (; e + 8 <= e2; e += 8) {
        int s0 = nbr[e],     s1 = nbr[e + 1], s2 = nbr[e + 2], s3 = nbr[e + 3];
        int s4 = nbr[e + 4], s5 = nbr[e + 5], s6 = nbr[e + 6], s7 = nbr[e + 7];
        unsigned v0 = h2[s0 * 64 + lane];
        unsigned v1 = h2[s1 * 64 + lane];
        unsigned v2 = h2[s2 * 64 + lane];
        unsigned v3 = h2[s3 * 64 + lane];
        unsigned v4 = h2[s4 * 64 + lane];
        unsigned v5 = h2[s5 * 64 + lane];
        unsigned v6 = h2[s6 * 64 + lane];
        unsigned v7 = h2[s7 * 64 + lane];
        a0 += (bf2f((ushort)(v0 & 0xffffu)) + bf2f((ushort)(v1 & 0xffffu)))
            + (bf2f((ushort)(v2 & 0xffffu)) + bf2f((ushort)(v3 & 0xffffu)))
            + (bf2f((ushort)(v4 & 0xffffu)) + bf2f((ushort)(v5 & 0xffffu)))
            + (bf2f((ushort)(v6 & 0xffffu)) + bf2f((ushort)(v7 & 0xffffu)));
        a1 += (bf2f((ushort)(v0 >> 16)) + bf2f((ushort)(v1 >> 16)))
            + (bf2f((ushort)(v2 >> 16)) + bf2f((ushort)(v3 >> 16)))
            + (bf2f((ushort)(v4 >> 16)) + bf2f((ushort)(v5 >> 16)))
            + (bf2f((ushort)(v6 >> 16)) + bf2f((ushort)(v7 >> 16)));
    }
    for (; e + 2 <= e2; e += 2) {
        unsigned v0 = h2[nbr[e] * 64 + lane];
        unsigned v1 = h2[nbr[e + 1] * 64 + lane];
        a0 += bf2f((ushort)(v0 & 0xffffu)) + bf2f((ushort)(v1 & 0xffffu));
        a1 += bf2f((ushort)(v0 >> 16)) + bf2f((ushort)(v1 >> 16));
    }
    if (e < e2) {
        unsigned v = h2[nbr[e] * 64 + lane];
        a0 += bf2f((ushort)(v & 0xffffu));
        a1 += bf2f((ushort)(v >> 16));
    }
    float inv = 1.0f / fmaxf((float)(e2 - b), 1.0f);
    unsigned o = (unsigned)f2bf(a0 * inv) | ((unsigned)f2bf(a1 * inv) << 16);
    ((unsigned*)agg1)[node * 64 + lane] = o;
}

// ---------------- dense0: h0 = relu([agg0|x] @ [Wl0;Wr0]^T + bl0), MFMA ----------------
__global__ __launch_bounds__(256) void dense0_k(
    const ushort* __restrict__ xb, const ushort* __restrict__ agg0,
    const ushort* __restrict__ wbt0, const float* __restrict__ bl,
    ushort* __restrict__ h0)
{
    __shared__ ushort bt[128 * 128];   // pre-swizzled image, 32 KB
    __shared__ float  bl_s[128];

    #pragma unroll
    for (int c = 0; c < 8; ++c) {
        int i = threadIdx.x + c * 256;
        ((short8*)bt)[i] = ((const short8*)wbt0)[i];
    }
    if (threadIdx.x < 128) bl_s[threadIdx.x] = bl[threadIdx.x];
    __syncthreads();

    int w = threadIdx.x >> 6, l = threadIdx.x & 63;
    int l15 = l & 15, hi = l >> 4;
    int row  = blockIdx.x * 64 + w * 16 + l15;
    int rowc = row < NN ? row : 0;

    short8 a[4];
    a[0] = *(const short8*)(agg0 + rowc * 64 + hi * 8);
    a[1] = *(const short8*)(agg0 + rowc * 64 + 32 + hi * 8);
    a[2] = *(const short8*)(xb + rowc * 64 + hi * 8);
    a[3] = *(const short8*)(xb + rowc * 64 + 32 + hi * 8);

    f32x4 acc[8];
    #pragma unroll
    for (int nt = 0; nt < 8; ++nt) acc[nt] = (f32x4){0.f, 0.f, 0.f, 0.f};

    #pragma unroll
    for (int ks = 0; ks < 4; ++ks) {
        #pragma unroll
        for (int nt = 0; nt < 8; ++nt) {
            int byte = ((nt * 16 + l15) * 256 + (ks * 32 + hi * 8) * 2) ^ ((l15 & 7) << 4);
            short8 bfr = *(const short8*)((const char*)bt + byte);
            acc[nt] = __builtin_amdgcn_mfma_f32_16x16x32_bf16(a[ks], bfr, acc[nt], 0, 0, 0);
        }
    }

    int rowbase = blockIdx.x * 64 + w * 16 + hi * 4;
    #pragma unroll
    for (int r = 0; r < 4; ++r) {
        int ro = rowbase + r;
        if (ro < NN) {
            #pragma unroll
            for (int nt = 0; nt < 8; ++nt) {
                int col = nt * 16 + l15;
                float v = fmaxf(acc[nt][r] + bl_s[col], 0.f);
                h0[ro * 128 + col] = f2bf(v);
            }
        }
    }
}

// ---------------- dense1 + fc fused ----------------
__global__ __launch_bounds__(256) void dense1_k(
    const ushort* __restrict__ h0, const ushort* __restrict__ agg1,
    const ushort* __restrict__ wbt1, const float* __restrict__ bl,
    const float* __restrict__ Wfc, const float* __restrict__ bfc,
    float* __restrict__ out)
{
    __shared__ ushort bt[256 * 128];   // pre-swizzled image, 64 KB
    __shared__ float  bl_s[128];
    __shared__ float  wfc_s[256];

    #pragma unroll
    for (int c = 0; c < 16; ++c) {
        int i = threadIdx.x + c * 256;
        ((short8*)bt)[i] = ((const short8*)wbt1)[i];
    }
    if (threadIdx.x < 128) bl_s[threadIdx.x] = bl[threadIdx.x];
    if (threadIdx.x < 256) wfc_s[threadIdx.x] = Wfc[threadIdx.x];
    __syncthreads();

    int w = threadIdx.x >> 6, l = threadIdx.x & 63;
    int l15 = l & 15, hi = l >> 4;
    int row  = blockIdx.x * 64 + w * 16 + l15;
    int rowc = row < NN ? row : 0;

    short8 a[8];
    #pragma unroll
    for (int ks = 0; ks < 4; ++ks)
        a[ks] = *(const short8*)(agg1 + rowc * 128 + ks * 32 + hi * 8);
    #pragma unroll
    for (int ks = 0; ks < 4; ++ks)
        a[4 + ks] = *(const short8*)(h0 + rowc * 128 + ks * 32 + hi * 8);

    f32x4 acc[8];
    #pragma unroll
    for (int nt = 0; nt < 8; ++nt) acc[nt] = (f32x4){0.f, 0.f, 0.f, 0.f};

    #pragma unroll
    for (int ks = 0; ks < 8; ++ks) {
        #pragma unroll
        for (int nt = 0; nt < 8; ++nt) {
            int byte = ((nt * 16 + l15) * 512 + (ks * 32 + hi * 8) * 2) ^ ((l15 & 7) << 4);
            short8 bfr = *(const short8*)((const char*)bt + byte);
            acc[nt] = __builtin_amdgcn_mfma_f32_16x16x32_bf16(a[ks], bfr, acc[nt], 0, 0, 0);
        }
    }

    int rowbase = blockIdx.x * 64 + w * 16 + hi * 4;
    #pragma unroll
    for (int r = 0; r < 4; ++r) {
        float p0 = 0.f, p1 = 0.f;
        #pragma unroll
        for (int nt = 0; nt < 8; ++nt) {
            int col = nt * 16 + l15;
            float h1 = fmaxf(acc[nt][r] + bl_s[col], 0.f);
            p0 += h1 * wfc_s[col];
            p1 += h1 * wfc_s[128 + col];
        }
        p0 += __shfl_xor(p0, 1, 64); p0 += __shfl_xor(p0, 2, 64);
        p0 += __shfl_xor(p0, 4, 64); p0 += __shfl_xor(p0, 8, 64);
        p1 += __shfl_xor(p1, 1, 64); p1 += __shfl_xor(p1, 2, 64);
        p1 += __shfl_xor(p1, 4, 64); p1 += __shfl_xor(p1, 8, 64);
        int ro = rowbase + r;
        if (l15 == 0 && ro < NN) {
            float2 o; o.x = p0 + bfc[0]; o.y = p1 + bfc[1];
            *(float2*)(out + ro * 2) = o;
        }
    }
}

extern "C" void kernel_launch(void* const* d_in, const int* in_sizes, int n_in,
                              void* d_out, int out_size, void* d_ws, size_t ws_size,
                              hipStream_t stream)
{
    const float* x   = (const float*)d_in[0];
    const int*   ei  = (const int*)d_in[1];
    const float* Wl0 = (const float*)d_in[2];
    const float* bl0 = (const float*)d_in[3];
    const float* Wr0 = (const float*)d_in[4];
    const float* Wl1 = (const float*)d_in[5];
    const float* bl1 = (const float*)d_in[6];
    const float* Wr1 = (const float*)d_in[7];
    const float* Wfc = (const float*)d_in[8];
    const float* bfc = (const float*)d_in[9];
    float* out = (float*)d_out;

    const int* src = ei;
    const int* dst = ei + NE;

    // ws layout (bytes):
    //   deg    @ 0          (200,000)   <- memset
    //   rowptr @ 200,000    (200,004)
    //   rank   @ 400,004    (3,200,000)
    //   nbr    @ 3,600,004  (3,200,000)
    //   aggB   @ 6,800,016  (12,800,000)  agg0 (NN*64*2B) / agg1 (NN*128*2B) share
    //   h0B    @ 19,600,016 (12,800,000)
    //   bsum   @ 32,400,016 (784)
    //   boff   @ 32,400,800 (784)        (unused now)
    //   xb     @ 32,401,600 (6,400,000)
    //   wbt0   @ 38,801,600 (32,768)
    //   wbt1   @ 38,834,368 (65,536)
    char*   ws     = (char*)d_ws;
    int*    deg    = (int*)(ws);
    int*    rowptr = (int*)(ws + 200000);
    int*    rank   = (int*)(ws + 400004);
    int*    nbr    = (int*)(ws + 3600004);
    ushort* aggB   = (ushort*)(ws + 6800016);
    ushort* h0B    = (ushort*)(ws + 19600016);
    int*    bsum   = (int*)(ws + 32400016);
    ushort* xb     = (ushort*)(ws + 32401600);
    ushort* wbt0   = (ushort*)(ws + 38801600);
    ushort* wbt1   = (ushort*)(ws + 38834368);

    hipMemsetAsync(deg, 0, 200000, stream);

    count_k  <<<3125, 256, 0, stream>>>(dst, deg, rank, x, xb,
                                        Wl0, Wr0, Wl1, Wr1, wbt0, wbt1);
    partial_k<<<NB, 256, 0, stream>>>(deg, bsum);
    emit_k   <<<NB, 256, 0, stream>>>(deg, bsum, rowptr);
    fill_k   <<<3125, 256, 0, stream>>>(src, dst, rowptr, rank, nbr);

    gather0_k<<<12500, 256, 0, stream>>>(xb, rowptr, nbr, aggB);
    dense0_k <<<782, 256, 0, stream>>>(xb, aggB, wbt0, bl0, h0B);
    gather1_k<<<12500, 256, 0, stream>>>(h0B, rowptr, nbr, aggB);
    dense1_k <<<782, 256, 0, stream>>>(h0B, aggB, wbt1, bl1, Wfc, bfc, out);
}

// Round 8
// 142.192 us; speedup vs baseline: 6.3482x; 1.0461x over previous
//
#include <hip/hip_runtime.h>
#include <hip/hip_bf16.h>

#define NN   50000
#define NE   800000
#define NB   196   // ceil(NN/256)

typedef __attribute__((ext_vector_type(8))) short short8;
typedef __attribute__((ext_vector_type(4))) float f32x4;

static __device__ __forceinline__ ushort f2bf(float f) {
    union { float f; unsigned u; } v; v.f = f;
    unsigned r = v.u + 0x7fffu + ((v.u >> 16) & 1u);   // round-to-nearest-even
    return (ushort)(r >> 16);
}
static __device__ __forceinline__ float bf2f(ushort h) {
    union { unsigned u; float f; } v; v.u = ((unsigned)h) << 16;
    return v.f;
}

// ---------------- count (+rank) + x->bf16 + weight-image prep ----------------
__global__ __launch_bounds__(256) void count_k(
    const int* __restrict__ dst, int* __restrict__ deg,
    int* __restrict__ rank,
    const float* __restrict__ x, ushort* __restrict__ xb,
    const float* __restrict__ Wl0, const float* __restrict__ Wr0,
    const float* __restrict__ Wl1, const float* __restrict__ Wr1,
    ushort* __restrict__ wbt0, ushort* __restrict__ wbt1)
{
    int gid = blockIdx.x * 256 + threadIdx.x;

    if (gid < 2048) {
        {   // dense0 image
            int c = gid;
            int n  = c >> 4;
            int kc = (c & 15) * 8;
            const float* wsrc = (kc < 64) ? (Wl0 + n * 64 + kc) : (Wr0 + n * 64 + (kc - 64));
            float4 f0 = *(const float4*)(wsrc);
            float4 f1 = *(const float4*)(wsrc + 4);
            short8 v;
            v[0] = f2bf(f0.x); v[1] = f2bf(f0.y); v[2] = f2bf(f0.z); v[3] = f2bf(f0.w);
            v[4] = f2bf(f1.x); v[5] = f2bf(f1.y); v[6] = f2bf(f1.z); v[7] = f2bf(f1.w);
            int byte = (n * 256 + kc * 2) ^ ((n & 7) << 4);
            *(short8*)((char*)wbt0 + byte) = v;
        }
        #pragma unroll
        for (int rep = 0; rep < 2; ++rep) {   // dense1 image
            int c = gid + rep * 2048;
            int n  = c >> 5;
            int kc = (c & 31) * 8;
            const float* wsrc = (kc < 128) ? (Wl1 + n * 128 + kc) : (Wr1 + n * 128 + (kc - 128));
            float4 f0 = *(const float4*)(wsrc);
            float4 f1 = *(const float4*)(wsrc + 4);
            short8 v;
            v[0] = f2bf(f0.x); v[1] = f2bf(f0.y); v[2] = f2bf(f0.z); v[3] = f2bf(f0.w);
            v[4] = f2bf(f1.x); v[5] = f2bf(f1.y); v[6] = f2bf(f1.z); v[7] = f2bf(f1.w);
            int byte = (n * 512 + kc * 2) ^ ((n & 7) << 4);
            *(short8*)((char*)wbt1 + byte) = v;
        }
    }

    int base = gid * 4;
    float4 f = *(const float4*)(x + base);
    ushort4 o;
    o.x = f2bf(f.x); o.y = f2bf(f.y); o.z = f2bf(f.z); o.w = f2bf(f.w);
    *(ushort4*)(xb + base) = o;

    int d = dst[gid];
    rank[gid] = atomicAdd(&deg[d], 1);
}

__global__ __launch_bounds__(256) void partial_k(
    const int* __restrict__ deg, int* __restrict__ bsum)
{
    int gid = blockIdx.x * 256 + threadIdx.x;
    int v = (gid < NN) ? deg[gid] : 0;
    #pragma unroll
    for (int off = 32; off > 0; off >>= 1) v += __shfl_xor(v, off, 64);
    __shared__ int wsum[4];
    if ((threadIdx.x & 63) == 0) wsum[threadIdx.x >> 6] = v;
    __syncthreads();
    if (threadIdx.x == 0)
        bsum[blockIdx.x] = wsum[0] + wsum[1] + wsum[2] + wsum[3];
}

__global__ __launch_bounds__(256) void emit_k(
    const int* __restrict__ deg, const int* __restrict__ bsum,
    int* __restrict__ rowptr)
{
    __shared__ int s[256], sb[256];
    int tid = threadIdx.x;
    int gid = blockIdx.x * 256 + tid;
    int v  = (gid < NN) ? deg[gid] : 0;
    int bv = (tid < NB) ? bsum[tid] : 0;
    s[tid] = v; sb[tid] = bv;
    __syncthreads();
    for (int off = 1; off < 256; off <<= 1) {
        int a1 = (tid >= off) ? s[tid - off] : 0;
        int a2 = (tid >= off) ? sb[tid - off] : 0;
        __syncthreads();
        s[tid] += a1; sb[tid] += a2;
        __syncthreads();
    }
    int boff = (blockIdx.x == 0) ? 0 : sb[blockIdx.x - 1];
    if (gid < NN) rowptr[gid] = boff + s[tid] - v;
    if (blockIdx.x == 0 && tid == 0) rowptr[NN] = NE;
}

__global__ __launch_bounds__(256) void fill_k(
    const int* __restrict__ src, const int* __restrict__ dst,
    const int* __restrict__ rowptr, const int* __restrict__ rank,
    int* __restrict__ nbr)
{
    int e = blockIdx.x * 256 + threadIdx.x;
    int d = dst[e];
    nbr[rowptr[d] + rank[e]] = src[e];
}

// ---------------- gather0: 8 groups x 8 lanes, 16B/lane, 16 edges in flight ----------------
__global__ __launch_bounds__(256) void gather0_k(
    const ushort* __restrict__ xb, const int* __restrict__ rowptr,
    const int* __restrict__ nbr, ushort* __restrict__ agg0)
{
    int gid  = blockIdx.x * 256 + threadIdx.x;
    int lane = gid & 63;
    int node = gid >> 6;
    if (node >= NN) return;
    int g   = lane >> 3;      // edge-group 0..7
    int sub = lane & 7;       // feature octet 0..7
    int b = rowptr[node], e2 = rowptr[node + 1];
    float acc[8];
    #pragma unroll
    for (int j = 0; j < 8; ++j) acc[j] = 0.f;

    int e = b;
    for (; e + 16 <= e2; e += 16) {
        int sA = nbr[e + g];
        int sB = nbr[e + 8 + g];
        short8 vA = *(const short8*)(xb + sA * 64 + sub * 8);
        short8 vB = *(const short8*)(xb + sB * 64 + sub * 8);
        #pragma unroll
        for (int j = 0; j < 8; ++j)
            acc[j] += bf2f((ushort)vA[j]) + bf2f((ushort)vB[j]);
    }
    for (; e < e2; e += 8) {
        int eg = e + g;
        bool valid = eg < e2;
        int s = valid ? nbr[eg] : 0;
        short8 v = *(const short8*)(xb + s * 64 + sub * 8);
        float m = valid ? 1.f : 0.f;
        #pragma unroll
        for (int j = 0; j < 8; ++j)
            acc[j] += m * bf2f((ushort)v[j]);
    }

    #pragma unroll
    for (int j = 0; j < 8; ++j) {
        float t = acc[j];
        t += __shfl_xor(t, 8, 64);
        t += __shfl_xor(t, 16, 64);
        t += __shfl_xor(t, 32, 64);
        acc[j] = t;
    }
    if (g == 0) {
        float inv = 1.0f / fmaxf((float)(e2 - b), 1.0f);
        short8 o;
        #pragma unroll
        for (int j = 0; j < 8; ++j) o[j] = (short)f2bf(acc[j] * inv);
        *(short8*)(agg0 + node * 64 + sub * 8) = o;
    }
}

// ---------------- gather1: 4 groups x 16 lanes, 16B/lane, 8 edges in flight ----------------
__global__ __launch_bounds__(256) void gather1_k(
    const ushort* __restrict__ h0, const int* __restrict__ rowptr,
    const int* __restrict__ nbr, ushort* __restrict__ agg1)
{
    int gid  = blockIdx.x * 256 + threadIdx.x;
    int lane = gid & 63;
    int node = gid >> 6;
    if (node >= NN) return;
    int g   = lane >> 4;      // edge-group 0..3
    int sub = lane & 15;      // feature octet 0..15
    int b = rowptr[node], e2 = rowptr[node + 1];
    float acc[8];
    #pragma unroll
    for (int j = 0; j < 8; ++j) acc[j] = 0.f;

    int e = b;
    for (; e + 8 <= e2; e += 8) {
        int sA = nbr[e + g];
        int sB = nbr[e + 4 + g];
        short8 vA = *(const short8*)(h0 + sA * 128 + sub * 8);
        short8 vB = *(const short8*)(h0 + sB * 128 + sub * 8);
        #pragma unroll
        for (int j = 0; j < 8; ++j)
            acc[j] += bf2f((ushort)vA[j]) + bf2f((ushort)vB[j]);
    }
    for (; e < e2; e += 4) {
        int eg = e + g;
        bool valid = eg < e2;
        int s = valid ? nbr[eg] : 0;
        short8 v = *(const short8*)(h0 + s * 128 + sub * 8);
        float m = valid ? 1.f : 0.f;
        #pragma unroll
        for (int j = 0; j < 8; ++j)
            acc[j] += m * bf2f((ushort)v[j]);
    }

    #pragma unroll
    for (int j = 0; j < 8; ++j) {
        float t = acc[j];
        t += __shfl_xor(t, 16, 64);
        t += __shfl_xor(t, 32, 64);
        acc[j] = t;
    }
    if (g == 0) {
        float inv = 1.0f / fmaxf((float)(e2 - b), 1.0f);
        short8 o;
        #pragma unroll
        for (int j = 0; j < 8; ++j) o[j] = (short)f2bf(acc[j] * inv);
        *(short8*)(agg1 + node * 128 + sub * 8) = o;
    }
}

// ---------------- dense0: h0 = relu([agg0|x] @ [Wl0;Wr0]^T + bl0), MFMA ----------------
__global__ __launch_bounds__(256) void dense0_k(
    const ushort* __restrict__ xb, const ushort* __restrict__ agg0,
    const ushort* __restrict__ wbt0, const float* __restrict__ bl,
    ushort* __restrict__ h0)
{
    __shared__ ushort bt[128 * 128];   // pre-swizzled image, 32 KB
    __shared__ float  bl_s[128];

    #pragma unroll
    for (int c = 0; c < 8; ++c) {
        int i = threadIdx.x + c * 256;
        ((short8*)bt)[i] = ((const short8*)wbt0)[i];
    }
    if (threadIdx.x < 128) bl_s[threadIdx.x] = bl[threadIdx.x];
    __syncthreads();

    int w = threadIdx.x >> 6, l = threadIdx.x & 63;
    int l15 = l & 15, hi = l >> 4;
    int row  = blockIdx.x * 64 + w * 16 + l15;
    int rowc = row < NN ? row : 0;

    short8 a[4];
    a[0] = *(const short8*)(agg0 + rowc * 64 + hi * 8);
    a[1] = *(const short8*)(agg0 + rowc * 64 + 32 + hi * 8);
    a[2] = *(const short8*)(xb + rowc * 64 + hi * 8);
    a[3] = *(const short8*)(xb + rowc * 64 + 32 + hi * 8);

    f32x4 acc[8];
    #pragma unroll
    for (int nt = 0; nt < 8; ++nt) acc[nt] = (f32x4){0.f, 0.f, 0.f, 0.f};

    #pragma unroll
    for (int ks = 0; ks < 4; ++ks) {
        #pragma unroll
        for (int nt = 0; nt < 8; ++nt) {
            int byte = ((nt * 16 + l15) * 256 + (ks * 32 + hi * 8) * 2) ^ ((l15 & 7) << 4);
            short8 bfr = *(const short8*)((const char*)bt + byte);
            acc[nt] = __builtin_amdgcn_mfma_f32_16x16x32_bf16(a[ks], bfr, acc[nt], 0, 0, 0);
        }
    }

    int rowbase = blockIdx.x * 64 + w * 16 + hi * 4;
    #pragma unroll
    for (int r = 0; r < 4; ++r) {
        int ro = rowbase + r;
        if (ro < NN) {
            #pragma unroll
            for (int nt = 0; nt < 8; ++nt) {
                int col = nt * 16 + l15;
                float v = fmaxf(acc[nt][r] + bl_s[col], 0.f);
                h0[ro * 128 + col] = f2bf(v);
            }
        }
    }
}

// ---------------- dense1 + fc fused ----------------
__global__ __launch_bounds__(256) void dense1_k(
    const ushort* __restrict__ h0, const ushort* __restrict__ agg1,
    const ushort* __restrict__ wbt1, const float* __restrict__ bl,
    const float* __restrict__ Wfc, const float* __restrict__ bfc,
    float* __restrict__ out)
{
    __shared__ ushort bt[256 * 128];   // pre-swizzled image, 64 KB
    __shared__ float  bl_s[128];
    __shared__ float  wfc_s[256];

    #pragma unroll
    for (int c = 0; c < 16; ++c) {
        int i = threadIdx.x + c * 256;
        ((short8*)bt)[i] = ((const short8*)wbt1)[i];
    }
    if (threadIdx.x < 128) bl_s[threadIdx.x] = bl[threadIdx.x];
    if (threadIdx.x < 256) wfc_s[threadIdx.x] = Wfc[threadIdx.x];
    __syncthreads();

    int w = threadIdx.x >> 6, l = threadIdx.x & 63;
    int l15 = l & 15, hi = l >> 4;
    int row  = blockIdx.x * 64 + w * 16 + l15;
    int rowc = row < NN ? row : 0;

    short8 a[8];
    #pragma unroll
    for (int ks = 0; ks < 4; ++ks)
        a[ks] = *(const short8*)(agg1 + rowc * 128 + ks * 32 + hi * 8);
    #pragma unroll
    for (int ks = 0; ks < 4; ++ks)
        a[4 + ks] = *(const short8*)(h0 + rowc * 128 + ks * 32 + hi * 8);

    f32x4 acc[8];
    #pragma unroll
    for (int nt = 0; nt < 8; ++nt) acc[nt] = (f32x4){0.f, 0.f, 0.f, 0.f};

    #pragma unroll
    for (int ks = 0; ks < 8; ++ks) {
        #pragma unroll
        for (int nt = 0; nt < 8; ++nt) {
            int byte = ((nt * 16 + l15) * 512 + (ks * 32 + hi * 8) * 2) ^ ((l15 & 7) << 4);
            short8 bfr = *(const short8*)((const char*)bt + byte);
            acc[nt] = __builtin_amdgcn_mfma_f32_16x16x32_bf16(a[ks], bfr, acc[nt], 0, 0, 0);
        }
    }

    int rowbase = blockIdx.x * 64 + w * 16 + hi * 4;
    #pragma unroll
    for (int r = 0; r < 4; ++r) {
        float p0 = 0.f, p1 = 0.f;
        #pragma unroll
        for (int nt = 0; nt < 8; ++nt) {
            int col = nt * 16 + l15;
            float h1 = fmaxf(acc[nt][r] + bl_s[col], 0.f);
            p0 += h1 * wfc_s[col];
            p1 += h1 * wfc_s[128 + col];
        }
        p0 += __shfl_xor(p0, 1, 64); p0 += __shfl_xor(p0, 2, 64);
        p0 += __shfl_xor(p0, 4, 64); p0 += __shfl_xor(p0, 8, 64);
        p1 += __shfl_xor(p1, 1, 64); p1 += __shfl_xor(p1, 2, 64);
        p1 += __shfl_xor(p1, 4, 64); p1 += __shfl_xor(p1, 8, 64);
        int ro = rowbase + r;
        if (l15 == 0 && ro < NN) {
            float2 o; o.x = p0 + bfc[0]; o.y = p1 + bfc[1];
            *(float2*)(out + ro * 2) = o;
        }
    }
}

extern "C" void kernel_launch(void* const* d_in, const int* in_sizes, int n_in,
                              void* d_out, int out_size, void* d_ws, size_t ws_size,
                              hipStream_t stream)
{
    const float* x   = (const float*)d_in[0];
    const int*   ei  = (const int*)d_in[1];
    const float* Wl0 = (const float*)d_in[2];
    const float* bl0 = (const float*)d_in[3];
    const float* Wr0 = (const float*)d_in[4];
    const float* Wl1 = (const float*)d_in[5];
    const float* bl1 = (const float*)d_in[6];
    const float* Wr1 = (const float*)d_in[7];
    const float* Wfc = (const float*)d_in[8];
    const float* bfc = (const float*)d_in[9];
    float* out = (float*)d_out;

    const int* src = ei;
    const int* dst = ei + NE;

    char*   ws     = (char*)d_ws;
    int*    deg    = (int*)(ws);
    int*    rowptr = (int*)(ws + 200000);
    int*    rank   = (int*)(ws + 400004);
    int*    nbr    = (int*)(ws + 3600004);
    ushort* aggB   = (ushort*)(ws + 6800016);
    ushort* h0B    = (ushort*)(ws + 19600016);
    int*    bsum   = (int*)(ws + 32400016);
    ushort* xb     = (ushort*)(ws + 32401600);
    ushort* wbt0   = (ushort*)(ws + 38801600);
    ushort* wbt1   = (ushort*)(ws + 38834368);

    hipMemsetAsync(deg, 0, 200000, stream);

    count_k  <<<3125, 256, 0, stream>>>(dst, deg, rank, x, xb,
                                        Wl0, Wr0, Wl1, Wr1, wbt0, wbt1);
    partial_k<<<NB, 256, 0, stream>>>(deg, bsum);
    emit_k   <<<NB, 256, 0, stream>>>(deg, bsum, rowptr);
    fill_k   <<<3125, 256, 0, stream>>>(src, dst, rowptr, rank, nbr);

    gather0_k<<<12500, 256, 0, stream>>>(xb, rowptr, nbr, aggB);
    dense0_k <<<782, 256, 0, stream>>>(xb, aggB, wbt0, bl0, h0B);
    gather1_k<<<12500, 256, 0, stream>>>(h0B, rowptr, nbr, aggB);
    dense1_k <<<782, 256, 0, stream>>>(h0B, aggB, wbt1, bl1, Wfc, bfc, out);
}